// Round 30
// baseline (322.503 us; speedup 1.0000x reference)
//
#include <hip/hip_runtime.h>

constexpr int NB = 2;
constexpr int NC = 48;
constexpr int NH = 256;
constexpr int NW = 256;
constexpr int NP = NH * NW;           // 65536
constexpr int NHEADS = 8;
constexpr int NCHD = 6;
constexpr int NHID = 96;
constexpr int GSEG = 32;              // gram segments per (b,h)

typedef unsigned short bf16_t;
typedef __attribute__((ext_vector_type(8))) short bf16x8;
typedef __attribute__((ext_vector_type(4))) float f32x4;

__device__ __forceinline__ float bf2f(bf16_t u) {
  union { unsigned int i; float f; } c; c.i = ((unsigned int)u) << 16; return c.f;
}
__device__ __forceinline__ bf16_t f2bf(float f) {
  union { float f; unsigned int i; } c; c.f = f;
  unsigned int r = (c.i + 0x7FFFu + ((c.i >> 16) & 1u)) >> 16;
  return (bf16_t)r;
}
__device__ __forceinline__ void unpack2(unsigned int u, float& a, float& b) {
  union { unsigned int i; float f; } c0, c1;
  c0.i = u << 16; c1.i = u & 0xffff0000u;
  a = c0.f; b = c1.f;
}

// tanh-form GELU via fast exp (max dev vs erf-form ~3e-4)
__device__ __forceinline__ float gelu_f(float v) {
  float u = v * (0.79788456f + 0.0356774081f * v * v);
  u = fminf(fmaxf(u, -9.f), 9.f);
  float e = __expf(-2.f * u);
  float th = (1.f - e) / (1.f + e);
  return 0.5f * v * (1.f + th);
}

// tap loop over a 12-float window (3x ds_read_b128), compile-time indices.
#define STENCIL_ROW(LROW, D, WVAL0, WVAL1, WVAL2, ACC)                        \
  {                                                                            \
    const float* lp = &lds[(LROW) * 272 + quad * 4];                           \
    float4 va = *(const float4*)lp;                                            \
    float4 vb = *(const float4*)(lp + 4);                                      \
    float4 vc = *(const float4*)(lp + 8);                                      \
    float v[12] = {va.x, va.y, va.z, va.w, vb.x, vb.y, vb.z, vb.w,             \
                   vc.x, vc.y, vc.z, vc.w};                                    \
    _Pragma("unroll") for (int jj = 0; jj < 4; ++jj) {                         \
      ACC[jj] = fmaf(v[jj - (D) + 4], WVAL0, ACC[jj]);                         \
      ACC[jj] = fmaf(v[jj + 4], WVAL1, ACC[jj]);                               \
      ACC[jj] = fmaf(v[jj + (D) + 4], WVAL2, ACC[jj]);                         \
    }                                                                          \
  }

// ---------------- conv1 weight prepack: per-tap MFMA A-fragments ----------------
__global__ void k_prepw(const float* __restrict__ cvw0, bf16_t* __restrict__ WC) {
  int i = blockIdx.x * blockDim.x + threadIdx.x;
  if (i >= 9 * 3 * 2 * 512) return;
  int j = i & 7, lane = (i >> 3) & 63;
  int fi = i >> 9;
  int s = fi & 1;
  int tot = fi >> 1;
  int ot = tot % 3, t = tot / 3;
  int o = ot * 16 + (lane & 15);
  int k = s * 32 + ((lane >> 4) << 3) + j;
  float v = (k < 48) ? cvw0[(size_t)(o * 48 + k) * 9 + t] : 0.f;
  WC[i] = f2bf(v);
}

// ---------------- conv1 via MFMA: 8x8 out tile, split-K, vectorized interior staging ----------------
__global__ __launch_bounds__(512) void k_conv1_mfma(const float* __restrict__ in,
                                                    const bf16_t* __restrict__ WC,
                                                    const float* __restrict__ bias,
                                                    bf16_t* __restrict__ out) {
  __shared__ bf16_t xs[17 * 17 * 72];   // 41616 B, [iy][ix][ic] ic-stride 72
  __shared__ float red[4 * 3 * 64 * 4]; // 12288 B split-K partials
  int blk = blockIdx.x;
  int tx = blk & 15;
  int t0 = blk >> 4;
  int ty = t0 & 15, b = t0 >> 4;
  int oy0 = ty * 8, ox0 = tx * 8;
  int iy0 = oy0 * 2 - 1, ix0 = ox0 * 2 - 1;
  const float* inb = in + (size_t)b * NC * NP;
  if (tx > 0 && ty > 0) {
    // interior: rows fully in-bounds; 5 aligned float4 per 17-wide row
    int bx = ix0 - 3;  // byte offset 16*(4*tx-1) -> 16B aligned
    for (int v = threadIdx.x; v < 48 * 17 * 5; v += 512) {
      int part = v % 5;
      int row = v / 5;
      int rr = row % 17;
      int ic = row / 17;
      const float* src = inb + ((size_t)ic << 16) + ((size_t)(iy0 + rr) << 8) + bx + part * 4;
      float4 f = *(const float4*)src;
      float fv[4] = {f.x, f.y, f.z, f.w};
      int cc0 = part * 4 - 3;
      #pragma unroll
      for (int e = 0; e < 4; ++e) {
        int cc = cc0 + e;
        if ((unsigned)cc < 17u) xs[(rr * 17 + cc) * 72 + ic] = f2bf(fv[e]);
      }
    }
  } else {
    for (int i = threadIdx.x; i < 17 * 17 * 48; i += 512) {
      int cc = i % 17;
      int t2 = i / 17;
      int rr = t2 % 17;
      int ic = t2 / 17;
      float v = 0.f;
      int iy = iy0 + rr, ix = ix0 + cc;
      if ((unsigned)iy < 256u && (unsigned)ix < 256u)
        v = inb[((size_t)ic << 16) + (iy << 8) + ix];
      xs[(rr * 17 + cc) * 72 + ic] = f2bf(v);
    }
  }
  for (int i = threadIdx.x; i < 289 * 16; i += 512) {  // zero-pad k 48..63
    int rcc = i >> 4, icz = i & 15;
    xs[rcc * 72 + 48 + icz] = 0;
  }
  __syncthreads();
  int wid = threadIdx.x >> 6, lane = threadIdx.x & 63;
  int pt = wid & 3, s = wid >> 2;
  int l15 = lane & 15, kl = lane >> 4;
  int px = pt * 16 + l15;
  int oy = px >> 3, ox = px & 7;
  int base = ((oy * 2) * 17 + ox * 2) * 72 + s * 32 + kl * 8;
  f32x4 acc[3] = {{0.f, 0.f, 0.f, 0.f}, {0.f, 0.f, 0.f, 0.f}, {0.f, 0.f, 0.f, 0.f}};
  #pragma unroll
  for (int t = 0; t < 9; ++t) {
    int dy = t / 3, dx = t % 3;  // compile-time
    bf16x8 bf = *(const bf16x8*)&xs[base + dy * (17 * 72) + dx * 72];
    #pragma unroll
    for (int ot = 0; ot < 3; ++ot) {
      bf16x8 af = *(const bf16x8*)(WC + (size_t)((t * 3 + ot) * 2 + s) * 512 + lane * 8);
      acc[ot] = __builtin_amdgcn_mfma_f32_16x16x32_bf16(af, bf, acc[ot], 0, 0, 0);
    }
  }
  if (s == 1) {
    #pragma unroll
    for (int ot = 0; ot < 3; ++ot)
      #pragma unroll
      for (int j = 0; j < 4; ++j)
        red[((pt * 3 + ot) * 64 + lane) * 4 + j] = acc[ot][j];
  }
  __syncthreads();
  if (s == 0) {
    bf16_t* ob = out + (size_t)b * NC * 16384;
    #pragma unroll
    for (int ot = 0; ot < 3; ++ot) {
      #pragma unroll
      for (int j = 0; j < 4; ++j) {
        int o = ot * 16 + kl * 4 + j;
        float r = acc[ot][j] + red[((pt * 3 + ot) * 64 + lane) * 4 + j] + bias[o];
        ob[((size_t)o * 128 + oy0 + oy) * 128 + ox0 + ox] = f2bf(r);
      }
    }
  }
}

// ---------------- conv-descriptor branch (conv2/conv3): ic-chunked, 8-wave blocks ----------------
__global__ __launch_bounds__(512) void k_conv_s2_tile(const float* __restrict__ in,
                                                      const float* __restrict__ w,
                                                      const float* __restrict__ bias,
                                                      float* __restrict__ out,
                                                      int IH, int IW, int OH, int OW) {
  __shared__ float lds[16 * 442];  // 16 ic * 17 rows * 26 = 28288 B
  int tilesX = OW >> 3;
  int tilesY = OH >> 3;
  int blk = blockIdx.x;
  int tx = blk % tilesX;
  int t = blk / tilesX;
  int ty = t % tilesY;
  int b = t / tilesY;
  int oy0 = ty * 8, ox0 = tx * 8;
  int iy0 = oy0 * 2 - 1, ix0 = ox0 * 2 - 1;
  const float* inb = in + (size_t)b * NC * IH * IW;

  int lane = threadIdx.x & 63;
  int oy = lane >> 3, ox = lane & 7;
  int ocb = __builtin_amdgcn_readfirstlane((threadIdx.x >> 6) * 6);
  float acc[6];
  #pragma unroll
  for (int j = 0; j < 6; ++j) acc[j] = bias[ocb + j];
  int rbase = oy * 52;  // row 2*oy, stride 26

  for (int chunk = 0; chunk < 3; ++chunk) {
    int icb = chunk * 16;
    for (int i = threadIdx.x; i < 16 * 17 * 17; i += 512) {
      int cc = i % 17;
      int t2 = i / 17;
      int rr = t2 % 17;
      int ic = t2 / 17;
      float v = 0.f;
      int iy = iy0 + rr, ix = ix0 + cc;
      if ((unsigned)iy < (unsigned)IH && (unsigned)ix < (unsigned)IW)
        v = inb[((size_t)(icb + ic) * IH + iy) * IW + ix];
      lds[ic * 442 + rr * 26 + ((cc & 1) ? 13 + (cc >> 1) : (cc >> 1))] = v;
    }
    __syncthreads();

    for (int ic16 = 0; ic16 < 16; ++ic16) {
      const float* base = lds + ic16 * 442 + rbase;
      float e0[3], e1[3], ov[3];
      #pragma unroll
      for (int ky = 0; ky < 3; ++ky) {
        const float* rowp = base + ky * 26;
        e0[ky] = rowp[ox];
        e1[ky] = rowp[ox + 1];
        ov[ky] = rowp[13 + ox];
      }
      const float* wpc = w + (size_t)(ocb * 48 + icb + ic16) * 9;
      #pragma unroll
      for (int j = 0; j < 6; ++j) {
        const float* wp = wpc + (size_t)j * 48 * 9;
        float a = acc[j];
        #pragma unroll
        for (int ky = 0; ky < 3; ++ky) {
          a = fmaf(wp[ky * 3 + 0], e0[ky], a);
          a = fmaf(wp[ky * 3 + 1], ov[ky], a);
          a = fmaf(wp[ky * 3 + 2], e1[ky], a);
        }
        acc[j] = a;
      }
    }
    __syncthreads();
  }

  float* ob = out + (size_t)b * NC * OH * OW;
  #pragma unroll
  for (int j = 0; j < 6; ++j)
    ob[((size_t)(ocb + j) * OH + oy0 + oy) * OW + ox0 + ox] = acc[j];
}

// ---------------- lnpool (f32 input): 4 sublanes share the channel loop ----------------
__global__ void k_lnpool(const float* __restrict__ in, const float* __restrict__ lw,
                         const float* __restrict__ lb, float* __restrict__ out,
                         int IH, int IW) {
  int OH = IH >> 1, OW = IW >> 1;
  int tid = blockIdx.x * blockDim.x + threadIdx.x;
  int idx = tid >> 2;
  int sl = tid & 3;        // channels sl*12 .. sl*12+11
  int total = NB * OH * OW;
  if (idx >= total) return;
  int ox = idx % OW;
  int t = idx / OW;
  int oy = t % OH;
  int b = t / OH;
  const float* inb = in + (size_t)b * NC * IH * IW;
  float vq[12][4];
  float s[4] = {0.f, 0.f, 0.f, 0.f}, ss[4] = {0.f, 0.f, 0.f, 0.f};
  #pragma unroll
  for (int cl = 0; cl < 12; ++cl) {
    int c = sl * 12 + cl;
    #pragma unroll
    for (int q = 0; q < 4; ++q) {
      int iy = oy * 2 + (q >> 1), ix = ox * 2 + (q & 1);
      float v = inb[((size_t)c * IH + iy) * IW + ix];
      vq[cl][q] = v;
      s[q] += v;
      ss[q] = fmaf(v, v, ss[q]);
    }
  }
  #pragma unroll
  for (int q = 0; q < 4; ++q) {
    s[q] += __shfl_xor(s[q], 1, 64);
    s[q] += __shfl_xor(s[q], 2, 64);
    ss[q] += __shfl_xor(ss[q], 1, 64);
    ss[q] += __shfl_xor(ss[q], 2, 64);
  }
  float mu[4], rs[4];
  #pragma unroll
  for (int q = 0; q < 4; ++q) {
    float m = s[q] * (1.f / NC);
    mu[q] = m;
    rs[q] = rsqrtf(fmaxf(ss[q] * (1.f / NC) - m * m, 0.f) + 1e-5f);
  }
  #pragma unroll
  for (int cl = 0; cl < 12; ++cl) {
    int c = sl * 12 + cl;
    float wv = lw[c], bv = lb[c];
    float best = 0.f;  // relu >= 0 so 0 == max of relu'd window
    #pragma unroll
    for (int q = 0; q < 4; ++q) {
      float v = (vq[cl][q] - mu[q]) * rs[q] * wv + bv;
      best = fmaxf(best, fmaxf(v, 0.f));
    }
    out[((size_t)(b * NC + c) * OH + oy) * OW + ox] = best;
  }
}

// ---------------- lnpool (bf16 input, stage 1) ----------------
__global__ void k_lnpool_b(const bf16_t* __restrict__ in, const float* __restrict__ lw,
                           const float* __restrict__ lb, float* __restrict__ out,
                           int IH, int IW) {
  int OH = IH >> 1, OW = IW >> 1;
  int tid = blockIdx.x * blockDim.x + threadIdx.x;
  int idx = tid >> 2;
  int sl = tid & 3;        // channels sl*12 .. sl*12+11
  int total = NB * OH * OW;
  if (idx >= total) return;
  int ox = idx % OW;
  int t = idx / OW;
  int oy = t % OH;
  int b = t / OH;
  const bf16_t* inb = in + (size_t)b * NC * IH * IW;
  float vq[12][4];
  float s[4] = {0.f, 0.f, 0.f, 0.f}, ss[4] = {0.f, 0.f, 0.f, 0.f};
  #pragma unroll
  for (int cl = 0; cl < 12; ++cl) {
    int c = sl * 12 + cl;
    #pragma unroll
    for (int q = 0; q < 4; ++q) {
      int iy = oy * 2 + (q >> 1), ix = ox * 2 + (q & 1);
      float v = bf2f(inb[((size_t)c * IH + iy) * IW + ix]);
      vq[cl][q] = v;
      s[q] += v;
      ss[q] = fmaf(v, v, ss[q]);
    }
  }
  #pragma unroll
  for (int q = 0; q < 4; ++q) {
    s[q] += __shfl_xor(s[q], 1, 64);
    s[q] += __shfl_xor(s[q], 2, 64);
    ss[q] += __shfl_xor(ss[q], 1, 64);
    ss[q] += __shfl_xor(ss[q], 2, 64);
  }
  float mu[4], rs[4];
  #pragma unroll
  for (int q = 0; q < 4; ++q) {
    float m = s[q] * (1.f / NC);
    mu[q] = m;
    rs[q] = rsqrtf(fmaxf(ss[q] * (1.f / NC) - m * m, 0.f) + 1e-5f);
  }
  #pragma unroll
  for (int cl = 0; cl < 12; ++cl) {
    int c = sl * 12 + cl;
    float wv = lw[c], bv = lb[c];
    float best = 0.f;
    #pragma unroll
    for (int q = 0; q < 4; ++q) {
      float v = (vq[cl][q] - mu[q]) * rs[q] * wv + bv;
      best = fmaxf(best, fmaxf(v, 0.f));
    }
    out[((size_t)(b * NC + c) * OH + oy) * OW + ox] = best;
  }
}

__global__ void k_head(const float* __restrict__ p3, const float* __restrict__ l2qw,
                       const float* __restrict__ l2qb, float* __restrict__ q0m) {
  __shared__ float xd[NC], q0[NC];
  int b = blockIdx.x, t = threadIdx.x;
  if (t < NC) {
    float s = 0.f;
    for (int i = 0; i < 16; ++i) s += p3[(b * NC + t) * 16 + i];
    xd[t] = gelu_f(s * (1.f / 16.f));
  }
  __syncthreads();
  if (t < NC) {
    float a = l2qb[t];
    for (int c = 0; c < NC; ++c) a += xd[c] * l2qw[t * NC + c];
    q0[t] = a;
  }
  __syncthreads();
  if (t < NHEADS * NCHD * NCHD) {
    int h = t / 36, r = t % 36, c = r / 6, d = r % 6;
    q0m[b * 288 + t] = q0[h * 6 + c] * q0[h * 6 + d];
  }
}

// ---------------- prep: S/B vectors + bf16 A-fragment-packed weights (qkv, pin, pout, proj) ----------------
__global__ void k_prep(const float* __restrict__ qkvw, const float* __restrict__ ln1w,
                       const float* __restrict__ ln1b, const float* __restrict__ pinw,
                       const float* __restrict__ ln2w, const float* __restrict__ ln2b,
                       const float* __restrict__ poutw, const float* __restrict__ projw,
                       float* __restrict__ SB, bf16_t* __restrict__ WA1,
                       bf16_t* __restrict__ WA2, bf16_t* __restrict__ WP,
                       bf16_t* __restrict__ WJ) {
  int t = blockIdx.x * blockDim.x + threadIdx.x;
  int stride = gridDim.x * blockDim.x;
  if (t < 144) {
    float s = 0.f, bb = 0.f;
    for (int c = 0; c < 48; ++c) {
      float w = qkvw[t * 48 + c];
      s = fmaf(w, ln1w[c], s); bb = fmaf(w, ln1b[c], bb);
    }
    SB[t] = s; SB[144 + t] = bb;
  } else if (t < 144 + 288) {
    int o = t - 144;
    float s = 0.f, bb = 0.f;
    for (int c = 0; c < 48; ++c) {
      float w = pinw[o * 48 + c];
      s = fmaf(w, ln2w[c], s); bb = fmaf(w, ln2b[c], bb);
    }
    SB[288 + o] = s; SB[576 + o] = bb;
  }
  for (int i = t; i < 9 * 1024; i += stride) {   // 144 oc: 9 ot * 2 s * 64 lane * 8 j
    int j = i & 7, lane = (i >> 3) & 63, s = (i >> 9) & 1, ot = i >> 10;
    int o = ot * 16 + (lane & 15);
    int k = s * 32 + ((lane >> 4) << 3) + j;
    float v = (k < 48) ? qkvw[o * 48 + k] * ln1w[k] : 0.f;
    WA1[i] = f2bf(v);
  }
  for (int i = t; i < 18 * 1024; i += stride) {  // 288 oc: 18 ot
    int j = i & 7, lane = (i >> 3) & 63, s = (i >> 9) & 1, ot = i >> 10;
    int o = ot * 16 + (lane & 15);
    int k = s * 32 + ((lane >> 4) << 3) + j;
    float v = (k < 48) ? pinw[o * 48 + k] * ln2w[k] : 0.f;
    WA2[i] = f2bf(v);
  }
  for (int i = t; i < 9 * 512; i += stride) {    // pout: 3 ot * 3 s * 512
    int j = i & 7, lane = (i >> 3) & 63;
    int fi = i >> 9;
    int s = fi % 3, ot = fi / 3;
    int o = ot * 16 + (lane & 15);
    int k = s * 32 + ((lane >> 4) << 3) + j;
    WP[i] = f2bf(poutw[o * 96 + k]);
  }
  for (int i = t; i < 6 * 512; i += stride) {    // proj: 3 ot * 2 s * 512
    int j = i & 7, lane = (i >> 3) & 63;
    int fi = i >> 9;
    int s = fi & 1, ot = fi >> 1;
    int o = ot * 16 + (lane & 15);
    int k = s * 32 + ((lane >> 4) << 3) + j;
    float v = (k < 48) ? projw[o * 48 + k] : 0.f;
    WJ[i] = f2bf(v);
  }
}

// ---------------- channel-mix via MFMA (swapped operands: D[pixel][o]) ----------------
// out[o][p] = rstd[p]*(mfma(xT,W')[p][o] - mu[p]*S[o]) + B[o]
__global__ __launch_bounds__(256) void k_chmix_mfma(const float* __restrict__ x,
                                                    const bf16_t* __restrict__ WA,
                                                    const float* __restrict__ S,
                                                    const float* __restrict__ Bc,
                                                    bf16_t* __restrict__ out,
                                                    int nout) {
  __shared__ bf16_t xT[64 * 72];       // 9216 B, row stride 72 (2-way bank alias)
  __shared__ float smu[64], srstd[64];
  int blk = blockIdx.x;
  int pxt = blk & 1023;
  int b = blk >> 10;
  int pbase = pxt * 64;
  const float* xb = x + (size_t)b * NC * NP + pbase;
  int p4 = threadIdx.x & 15, k0 = threadIdx.x >> 4;
  #pragma unroll
  for (int it = 0; it < 3; ++it) {
    int k = k0 + it * 16;
    float4 v = *(const float4*)(xb + (size_t)k * NP + p4 * 4);
    xT[(p4 * 4 + 0) * 72 + k] = f2bf(v.x);
    xT[(p4 * 4 + 1) * 72 + k] = f2bf(v.y);
    xT[(p4 * 4 + 2) * 72 + k] = f2bf(v.z);
    xT[(p4 * 4 + 3) * 72 + k] = f2bf(v.w);
  }
  {  // zero-pad k = 48..63
    int k = 48 + k0;
    xT[(p4 * 4 + 0) * 72 + k] = 0;
    xT[(p4 * 4 + 1) * 72 + k] = 0;
    xT[(p4 * 4 + 2) * 72 + k] = 0;
    xT[(p4 * 4 + 3) * 72 + k] = 0;
  }
  __syncthreads();
  if (threadIdx.x < 64) {
    int t = threadIdx.x;
    float s = 0.f, ss = 0.f;
    #pragma unroll
    for (int k4 = 0; k4 < 12; ++k4) {
      ushort4 u = *(const ushort4*)&xT[t * 72 + k4 * 4];
      float a0 = bf2f(u.x), a1 = bf2f(u.y), a2 = bf2f(u.z), a3 = bf2f(u.w);
      s += a0 + a1 + a2 + a3;
      ss = fmaf(a0, a0, ss); ss = fmaf(a1, a1, ss);
      ss = fmaf(a2, a2, ss); ss = fmaf(a3, a3, ss);
    }
    float mu = s * (1.f / NC);
    smu[t] = mu;
    srstd[t] = rsqrtf(fmaxf(ss * (1.f / NC) - mu * mu, 0.f) + 1e-5f);
  }
  int w = threadIdx.x >> 6;
  int lane = threadIdx.x & 63;
  bf16x8 bfr0 = *(const bf16x8*)&xT[(w * 16 + (lane & 15)) * 72 + ((lane >> 4) << 3)];
  bf16x8 bfr1 = *(const bf16x8*)&xT[(w * 16 + (lane & 15)) * 72 + 32 + ((lane >> 4) << 3)];
  __syncthreads();
  int pg = w * 16 + ((lane >> 4) << 2);      // 4-pixel group this lane owns
  float4 mu4 = *(const float4*)&smu[pg];
  float4 rs4 = *(const float4*)&srstd[pg];
  int p = pbase + pg;
  int nt = nout >> 4;
  bf16_t* ob = out + (size_t)b * nout * NP + p;
  for (int ot = 0; ot < nt; ++ot) {
    bf16x8 a0 = *(const bf16x8*)(WA + (size_t)(ot * 2 + 0) * 512 + lane * 8);
    bf16x8 a1 = *(const bf16x8*)(WA + (size_t)(ot * 2 + 1) * 512 + lane * 8);
    f32x4 acc = {0.f, 0.f, 0.f, 0.f};
    acc = __builtin_amdgcn_mfma_f32_16x16x32_bf16(bfr0, a0, acc, 0, 0, 0);
    acc = __builtin_amdgcn_mfma_f32_16x16x32_bf16(bfr1, a1, acc, 0, 0, 0);
    int o = ot * 16 + (lane & 15);
    float Sv = S[o], Bv = Bc[o];
    float r0 = fmaf(rs4.x, acc[0] - mu4.x * Sv, Bv);
    float r1 = fmaf(rs4.y, acc[1] - mu4.y * Sv, Bv);
    float r2 = fmaf(rs4.z, acc[2] - mu4.z * Sv, Bv);
    float r3 = fmaf(rs4.w, acc[3] - mu4.w * Sv, Bv);
    *(ushort4*)(ob + (size_t)o * NP) = make_ushort4(f2bf(r0), f2bf(r1), f2bf(r2), f2bf(r3));
  }
}

// ---------------- channel-mix via MFMA, bf16 input (swapped operands) ----------------
__global__ __launch_bounds__(256) void k_chmix_mfma_b(const bf16_t* __restrict__ x,
                                                      const bf16_t* __restrict__ WA,
                                                      const float* __restrict__ S,
                                                      const float* __restrict__ Bc,
                                                      bf16_t* __restrict__ out,
                                                      int nout) {
  __shared__ bf16_t xT[64 * 72];
  __shared__ float smu[64], srstd[64];
  int blk = blockIdx.x;
  int pxt = blk & 1023;
  int b = blk >> 10;
  int pbase = pxt * 64;
  const bf16_t* xb = x + (size_t)b * NC * NP + pbase;
  int p4 = threadIdx.x & 15, k0 = threadIdx.x >> 4;
  #pragma unroll
  for (int it = 0; it < 3; ++it) {
    int k = k0 + it * 16;
    ushort4 u = *(const ushort4*)(xb + (size_t)k * NP + p4 * 4);
    xT[(p4 * 4 + 0) * 72 + k] = u.x;
    xT[(p4 * 4 + 1) * 72 + k] = u.y;
    xT[(p4 * 4 + 2) * 72 + k] = u.z;
    xT[(p4 * 4 + 3) * 72 + k] = u.w;
  }
  {  // zero-pad k = 48..63
    int k = 48 + k0;
    xT[(p4 * 4 + 0) * 72 + k] = 0;
    xT[(p4 * 4 + 1) * 72 + k] = 0;
    xT[(p4 * 4 + 2) * 72 + k] = 0;
    xT[(p4 * 4 + 3) * 72 + k] = 0;
  }
  __syncthreads();
  if (threadIdx.x < 64) {
    int t = threadIdx.x;
    float s = 0.f, ss = 0.f;
    #pragma unroll
    for (int k4 = 0; k4 < 12; ++k4) {
      ushort4 u = *(const ushort4*)&xT[t * 72 + k4 * 4];
      float a0 = bf2f(u.x), a1 = bf2f(u.y), a2 = bf2f(u.z), a3 = bf2f(u.w);
      s += a0 + a1 + a2 + a3;
      ss = fmaf(a0, a0, ss); ss = fmaf(a1, a1, ss);
      ss = fmaf(a2, a2, ss); ss = fmaf(a3, a3, ss);
    }
    float mu = s * (1.f / NC);
    smu[t] = mu;
    srstd[t] = rsqrtf(fmaxf(ss * (1.f / NC) - mu * mu, 0.f) + 1e-5f);
  }
  int w = threadIdx.x >> 6;
  int lane = threadIdx.x & 63;
  bf16x8 bfr0 = *(const bf16x8*)&xT[(w * 16 + (lane & 15)) * 72 + ((lane >> 4) << 3)];
  bf16x8 bfr1 = *(const bf16x8*)&xT[(w * 16 + (lane & 15)) * 72 + 32 + ((lane >> 4) << 3)];
  __syncthreads();
  int pg = w * 16 + ((lane >> 4) << 2);
  float4 mu4 = *(const float4*)&smu[pg];
  float4 rs4 = *(const float4*)&srstd[pg];
  int p = pbase + pg;
  int nt = nout >> 4;
  bf16_t* ob = out + (size_t)b * nout * NP + p;
  for (int ot = 0; ot < nt; ++ot) {
    bf16x8 a0 = *(const bf16x8*)(WA + (size_t)(ot * 2 + 0) * 512 + lane * 8);
    bf16x8 a1 = *(const bf16x8*)(WA + (size_t)(ot * 2 + 1) * 512 + lane * 8);
    f32x4 acc = {0.f, 0.f, 0.f, 0.f};
    acc = __builtin_amdgcn_mfma_f32_16x16x32_bf16(bfr0, a0, acc, 0, 0, 0);
    acc = __builtin_amdgcn_mfma_f32_16x16x32_bf16(bfr1, a1, acc, 0, 0, 0);
    int o = ot * 16 + (lane & 15);
    float Sv = S[o], Bv = Bc[o];
    float r0 = fmaf(rs4.x, acc[0] - mu4.x * Sv, Bv);
    float r1 = fmaf(rs4.y, acc[1] - mu4.y * Sv, Bv);
    float r2 = fmaf(rs4.z, acc[2] - mu4.z * Sv, Bv);
    float r3 = fmaf(rs4.w, acc[3] - mu4.w * Sv, Bv);
    *(ushort4*)(ob + (size_t)o * NP) = make_ushort4(f2bf(r0), f2bf(r1), f2bf(r2), f2bf(r3));
  }
}

// ---------------- depthwise 3x3 on 144 channels (8-row stripe, bf16 in/out) ----------------
__global__ __launch_bounds__(256) void k_dw144(const bf16_t* __restrict__ in,
                                               const float* __restrict__ w9,
                                               bf16_t* __restrict__ out) {
  __shared__ float lds[10 * 272];  // 10880 B
  int blk = blockIdx.x;
  int rq = blk & 31;
  int ch = (blk >> 5) % 144;
  int b = blk / (144 * 32);
  int yy0 = rq * 8;
  const bf16_t* ib = in + (size_t)(b * 144 + ch) * NP;
  if (threadIdx.x < 40) {  // x-halo zeros: 10 rows x {slot0, 260,264,268}
    int sr = threadIdx.x >> 2, part = threadIdx.x & 3;
    int slot = (part == 0) ? 0 : (256 + part * 4);
    *(float4*)(&lds[sr * 272 + slot]) = make_float4(0.f, 0.f, 0.f, 0.f);
  }
  for (int i = threadIdx.x; i < 640; i += 256) {  // 10 rows x 64 float4 groups
    int sr = i >> 6, m = i & 63;
    int iy = yy0 + sr - 1;
    float4 v = make_float4(0.f, 0.f, 0.f, 0.f);
    if ((unsigned)iy < (unsigned)NH) {
      ushort4 u = *(const ushort4*)(ib + iy * NW + m * 4);
      v = make_float4(bf2f(u.x), bf2f(u.y), bf2f(u.z), bf2f(u.w));
    }
    *(float4*)(&lds[sr * 272 + 4 + m * 4]) = v;
  }
  __syncthreads();
  int q = threadIdx.x >> 6;
  int quad = threadIdx.x & 63;
  const float* wp = w9 + ch * 9;   // wave-uniform -> scalar loads
  bf16_t* ob = out + (size_t)(b * 144 + ch) * NP;
  #pragma unroll
  for (int half = 0; half < 2; ++half) {
    int orow = q + half * 4;
    float acc[4] = {0.f, 0.f, 0.f, 0.f};
    #pragma unroll
    for (int rr = 0; rr < 3; ++rr)
      STENCIL_ROW(orow + rr, 1, wp[rr * 3 + 0], wp[rr * 3 + 1], wp[rr * 3 + 2], acc);
    *(ushort4*)(ob + (yy0 + orow) * NW + quad * 4) =
        make_ushort4(f2bf(acc[0]), f2bf(acc[1]), f2bf(acc[2]), f2bf(acc[3]));
  }
}

// ---------------- per-head Gram (36) + channel ssq (12), GSEG=32, split-butterfly reduce ----------------
__global__ __launch_bounds__(256) void k_gram(const bf16_t* __restrict__ qkvd,
                                              float* __restrict__ spart) {
  int gid = blockIdx.x;  // b*256 + h*32 + seg
  int seg = gid & (GSEG - 1), h = (gid >> 5) & 7, b = gid >> 8;
  const bf16_t* qb = qkvd + (size_t)(b * 144 + h * 6) * NP;
  const bf16_t* kb = qkvd + (size_t)(b * 144 + 48 + h * 6) * NP;
  float acc[48];
  #pragma unroll
  for (int j = 0; j < 48; ++j) acc[j] = 0.f;
  #pragma unroll
  for (int it = 0; it < 2; ++it) {
    int p0 = seg * (NP / GSEG) + it * 1024 + threadIdx.x * 4;
    float qv[6][4], kv[6][4];
    #pragma unroll
    for (int c = 0; c < 6; ++c) {
      ushort4 uq = *(const ushort4*)(qb + (size_t)c * NP + p0);
      qv[c][0] = bf2f(uq.x); qv[c][1] = bf2f(uq.y); qv[c][2] = bf2f(uq.z); qv[c][3] = bf2f(uq.w);
      ushort4 uk = *(const ushort4*)(kb + (size_t)c * NP + p0);
      kv[c][0] = bf2f(uk.x); kv[c][1] = bf2f(uk.y); kv[c][2] = bf2f(uk.z); kv[c][3] = bf2f(uk.w);
    }
    #pragma unroll
    for (int px = 0; px < 4; ++px) {
      #pragma unroll
      for (int c = 0; c < 6; ++c)
        #pragma unroll
        for (int d = 0; d < 6; ++d)
          acc[c * 6 + d] = fmaf(qv[c][px], kv[d][px], acc[c * 6 + d]);
      #pragma unroll
      for (int c = 0; c < 6; ++c) acc[36 + c] = fmaf(qv[c][px], qv[c][px], acc[36 + c]);
      #pragma unroll
      for (int d = 0; d < 6; ++d) acc[42 + d] = fmaf(kv[d][px], kv[d][px], acc[42 + d]);
    }
  }
  int lane = threadIdx.x & 63, wid = threadIdx.x >> 6;
  // split-butterfly: halve the j-set at each xor step (compile-time indices)
  bool h1 = (lane & 32) != 0;
  float r1[24];
  #pragma unroll
  for (int m = 0; m < 24; ++m) {
    float keep = h1 ? acc[m + 24] : acc[m];
    float send = h1 ? acc[m] : acc[m + 24];
    r1[m] = keep + __shfl_xor(send, 32, 64);
  }
  bool h2 = (lane & 16) != 0;
  float r2[12];
  #pragma unroll
  for (int m = 0; m < 12; ++m) {
    float keep = h2 ? r1[m + 12] : r1[m];
    float send = h2 ? r1[m] : r1[m + 12];
    r2[m] = keep + __shfl_xor(send, 16, 64);
  }
  bool h3 = (lane & 8) != 0;
  float r3[6];
  #pragma unroll
  for (int m = 0; m < 6; ++m) {
    float keep = h3 ? r2[m + 6] : r2[m];
    float send = h3 ? r2[m] : r2[m + 6];
    r3[m] = keep + __shfl_xor(send, 8, 64);
  }
  bool h4 = (lane & 4) != 0;
  float r4[3];
  #pragma unroll
  for (int m = 0; m < 3; ++m) {
    float keep = h4 ? r3[m + 3] : r3[m];
    float send = h4 ? r3[m] : r3[m + 3];
    r4[m] = keep + __shfl_xor(send, 4, 64);
    r4[m] += __shfl_xor(r4[m], 2, 64);
    r4[m] += __shfl_xor(r4[m], 1, 64);
  }
  int jb = (h1 ? 24 : 0) + (h2 ? 12 : 0) + (h3 ? 6 : 0) + (h4 ? 3 : 0);
  __shared__ float sr[4 * 48];
  if ((lane & 3) == 0) {
    #pragma unroll
    for (int m = 0; m < 3; ++m) sr[wid * 48 + jb + m] = r4[m];
  }
  __syncthreads();
  if (threadIdx.x < 48)
    spart[(size_t)gid * 48 + threadIdx.x] =
        sr[threadIdx.x] + sr[48 + threadIdx.x] + sr[96 + threadIdx.x] + sr[144 + threadIdx.x];
}

// ---------------- attention softmax (cooperative seg reduce + softmax) ----------------
__global__ __launch_bounds__(256) void k_attn(const float* __restrict__ spart,
                                              const float* __restrict__ temp,
                                              const float* __restrict__ q0m,
                                              float* __restrict__ A) {
  int b = blockIdx.x;
  __shared__ float tot[8 * 48];
  for (int j = threadIdx.x; j < 384; j += 256) {
    int h = j / 48, v = j % 48;
    const float* base = spart + ((size_t)(b * 8 + h) * GSEG) * 48 + v;
    float s = 0.f;
    for (int seg = 0; seg < GSEG; ++seg) s += base[(size_t)seg * 48];
    tot[j] = s;
  }
  __syncthreads();
  int t = threadIdx.x;
  if (t >= 48) return;
  int h = t / 6, c = t % 6;
  const float* T = &tot[h * 48];
  float nq = fmaxf(sqrtf(T[36 + c]), 1e-12f);
  float tm = temp[h];
  float lg[6];
  #pragma unroll
  for (int d = 0; d < 6; ++d) {
    float nk = fmaxf(sqrtf(T[42 + d]), 1e-12f);
    lg[d] = (T[c * 6 + d] / (nq * nk)) * tm * q0m[b * 288 + h * 36 + c * 6 + d];
  }
  float m = lg[0];
  #pragma unroll
  for (int d = 1; d < 6; ++d) m = fmaxf(m, lg[d]);
  float sum = 0.f;
  #pragma unroll
  for (int d = 0; d < 6; ++d) { lg[d] = expf(lg[d] - m); sum += lg[d]; }
  float inv = 1.f / sum;
  #pragma unroll
  for (int d = 0; d < 6; ++d) A[b * 288 + h * 36 + c * 6 + d] = lg[d] * inv;
}

// ---------------- fc mix over the raw-reshape scramble (bf16 LDS staging, padded) ----------------
__global__ __launch_bounds__(384) void k_fc(const bf16_t* __restrict__ qkvd,
                                            const float* __restrict__ fcw,
                                            const float* __restrict__ fcb,
                                            bf16_t* __restrict__ fconv) {
  __shared__ bf16_t sin16[64 * 152];  // 19456 B, row stride 152 (uint4-aligned)
  __shared__ float sout[54 * 66];     // 14256 B, row stride 66
  int blk = blockIdx.x;
  int b = blk >> 10, p0 = (blk & 1023) << 6;
  const bf16_t* src = qkvd + (size_t)b * 144 * NP + (size_t)p0 * 144;
  const uint4* src4 = (const uint4*)src;
  for (int i = threadIdx.x; i < 1152; i += 384) {
    uint4 u = src4[i];
    int pix = i / 18, sub = i % 18;   // 18 uint4 (=144 bf16) per pixel
    *(uint4*)&sin16[pix * 152 + sub * 8] = u;
  }
  __syncthreads();
  int pl = threadIdx.x / 6, c2 = threadIdx.x % 6;
  float xv[24];
  #pragma unroll
  for (int g = 0; g < 24; ++g) xv[g] = bf2f(sin16[pl * 152 + g * 6 + c2]);
  #pragma unroll
  for (int o = 0; o < 9; ++o) {
    float a = fcb[o];
    #pragma unroll
    for (int g = 0; g < 24; ++g) a += fcw[o * 24 + g] * xv[g];
    sout[(c2 * 9 + o) * 66 + pl] = a;
  }
  __syncthreads();
  for (int i = threadIdx.x; i < 1728; i += 384) {
    int ch = i >> 5, pr = (i & 31) * 2;
    *(ushort2*)(fconv + (size_t)(b * 54 + ch) * NP + p0 + pr) =
        make_ushort2(f2bf(sout[ch * 66 + pr]), f2bf(sout[ch * 66 + pr + 1]));
  }
}

// ---------------- grouped dep conv 54->48 (4-row stripe, bf16 LDS staging) ----------------
__global__ __launch_bounds__(256, 4) void k_depconv(const bf16_t* __restrict__ fconv,
                                                    const float* __restrict__ dw,
                                                    const float* __restrict__ db,
                                                    bf16_t* __restrict__ outconv) {
  __shared__ bf16_t lds16[9 * 6 * 272];  // 29376 B
  int blk = blockIdx.x;               // b*6*64 + g*64 + rq
  int rq = blk & 63;
  int g = (blk >> 6) % 6;
  int b = blk / (6 * 64);
  int yy0 = rq * 4;
  const bf16_t* fb = fconv + (size_t)(b * 54 + g * 9) * NP;
  for (int i = threadIdx.x; i < 9 * 6 * 68; i += 256) {
    int j = i / 408;
    int rem = i % 408;
    int sr = rem / 68, c4 = rem % 68;
    int iy = yy0 + sr - 1;
    ushort4 v = make_ushort4(0, 0, 0, 0);
    if ((unsigned)iy < (unsigned)NH && c4 >= 1 && c4 <= 64)
      v = *(const ushort4*)(fb + (size_t)j * NP + iy * NW + (c4 - 1) * 4);
    *(ushort4*)(&lds16[(j * 6 + sr) * 272 + c4 * 4]) = v;
  }
  __syncthreads();
  int q = threadIdx.x >> 6;
  int quad = threadIdx.x & 63;
  float acc[8][4];
  #pragma unroll
  for (int o = 0; o < 8; ++o) {
    float bv = db[g * 8 + o];
    #pragma unroll
    for (int jj = 0; jj < 4; ++jj) acc[o][jj] = bv;
  }
  const float* wg = dw + (size_t)(g * 8) * 81;
  #pragma unroll
  for (int j = 0; j < 9; ++j) {
    #pragma unroll
    for (int rr = 0; rr < 3; ++rr) {
      const bf16_t* lp = &lds16[((j * 6) + q + rr) * 272 + quad * 4];
      ushort4 ua = *(const ushort4*)lp;
      ushort4 ub = *(const ushort4*)(lp + 4);
      ushort4 uc = *(const ushort4*)(lp + 8);
      float v[12] = {bf2f(ua.x), bf2f(ua.y), bf2f(ua.z), bf2f(ua.w),
                     bf2f(ub.x), bf2f(ub.y), bf2f(ub.z), bf2f(ub.w),
                     bf2f(uc.x), bf2f(uc.y), bf2f(uc.z), bf2f(uc.w)};
      #pragma unroll
      for (int dxi = 0; dxi < 3; ++dxi) {
        int wi = j * 9 + rr * 3 + dxi;
        #pragma unroll
        for (int o = 0; o < 8; ++o) {
          float wv = wg[o * 81 + wi];
          #pragma unroll
          for (int jj = 0; jj < 4; ++jj)
            acc[o][jj] = fmaf(v[jj + dxi + 3], wv, acc[o][jj]);
        }
      }
    }
  }
  bf16_t* ob = outconv + ((size_t)(b * NC + g * 8) * NH + yy0 + q) * NW + quad * 4;
  #pragma unroll
  for (int o = 0; o < 8; ++o)
    *(ushort4*)(ob + (size_t)o * NP) =
        make_ushort4(f2bf(acc[o][0]), f2bf(acc[o][1]), f2bf(acc[o][2]), f2bf(acc[o][3]));
}

// ---------------- proj via MFMA (swapped operands): x1(bf16) = x + projw@(A@V) + outconv ----------------
__global__ __launch_bounds__(256) void k_proj_mfma(const bf16_t* __restrict__ qkvd,
                                                   const float* __restrict__ A,
                                                   const bf16_t* __restrict__ WJ,
                                                   const float* __restrict__ x,
                                                   const bf16_t* __restrict__ outconv,
                                                   bf16_t* __restrict__ x1) {
  __shared__ bf16_t vT[64 * 72];   // 9216 B
  __shared__ bf16_t avT[64 * 72];  // 9216 B
  __shared__ float sA[288];
  int blk = blockIdx.x;
  int pxt = blk & 1023;
  int b = blk >> 10;
  int pbase = pxt * 64;
  const bf16_t* vb = qkvd + (size_t)(b * 144 + 96) * NP + pbase;
  int p4 = threadIdx.x & 15, k0 = threadIdx.x >> 4;
  #pragma unroll
  for (int it = 0; it < 3; ++it) {
    int k = k0 + it * 16;
    ushort4 u = *(const ushort4*)(vb + (size_t)k * NP + p4 * 4);
    vT[(p4 * 4 + 0) * 72 + k] = u.x;
    vT[(p4 * 4 + 1) * 72 + k] = u.y;
    vT[(p4 * 4 + 2) * 72 + k] = u.z;
    vT[(p4 * 4 + 3) * 72 + k] = u.w;
  }
  {  // zero-pad avT k = 48..63 (done by the k0 sweep: 16 values per px)
    int k = 48 + k0;
    avT[(p4 * 4 + 0) * 72 + k] = 0;
    avT[(p4 * 4 + 1) * 72 + k] = 0;
    avT[(p4 * 4 + 2) * 72 + k] = 0;
    avT[(p4 * 4 + 3) * 72 + k] = 0;
  }
  for (int i = threadIdx.x; i < 288; i += 256) sA[i] = A[b * 288 + i];
  __syncthreads();
  {  // A@V: 4 threads per pixel, 2 heads each
    int px = threadIdx.x & 63, hh = threadIdx.x >> 6;
    #pragma unroll
    for (int hi = 0; hi < 2; ++hi) {
      int h = hh * 2 + hi;
      float v6[6];
      #pragma unroll
      for (int d = 0; d < 6; ++d) v6[d] = bf2f(vT[px * 72 + h * 6 + d]);
      #pragma unroll
      for (int c = 0; c < 6; ++c) {
        float av = 0.f;
        #pragma unroll
        for (int d = 0; d < 6; ++d) av = fmaf(sA[h * 36 + c * 6 + d], v6[d], av);
        avT[px * 72 + h * 6 + c] = f2bf(av);
      }
    }
  }
  __syncthreads();
  int w = threadIdx.x >> 6;
  int lane = threadIdx.x & 63;
  int prow = w * 16 + (lane & 15);
  bf16x8 f0 = *(const bf16x8*)&avT[prow * 72 + ((lane >> 4) << 3)];
  bf16x8 f1 = *(const bf16x8*)&avT[prow * 72 + 32 + ((lane >> 4) << 3)];
  int pg = w * 16 + ((lane >> 4) << 2);
  int p = pbase + pg;
  const float* xb = x + (size_t)b * NC * NP + p;
  const bf16_t* ob = outconv + (size_t)b * NC * NP + p;
  bf16_t* x1b = x1 + (size_t)b * NC * NP + p;
  #pragma unroll
  for (int ot = 0; ot < 3; ++ot) {
    bf16x8 a0 = *(const bf16x8*)(WJ + (size_t)(ot * 2 + 0) * 512 + lane * 8);
    bf16x8 a1 = *(const bf16x8*)(WJ + (size_t)(ot * 2 + 1) * 512 + lane * 8);
    f32x4 acc = {0.f, 0.f, 0.f, 0.f};
    acc = __builtin_amdgcn_mfma_f32_16x16x32_bf16(f0, a0, acc, 0, 0, 0);
    acc = __builtin_amdgcn_mfma_f32_16x16x32_bf16(f1, a1, acc, 0, 0, 0);
    int o = ot * 16 + (lane & 15);
    float4 xv = *(const float4*)(xb + (size_t)o * NP);
    ushort4 ov = *(const ushort4*)(ob + (size_t)o * NP);
    *(ushort4*)(x1b + (size_t)o * NP) =
        make_ushort4(f2bf(xv.x + acc[0] + bf2f(ov.x)),
                     f2bf(xv.y + acc[1] + bf2f(ov.y)),
                     f2bf(xv.z + acc[2] + bf2f(ov.z)),
                     f2bf(xv.w + acc[3] + bf2f(ov.w)));
  }
}

// ---------------- FF: 3-dilation depthwise + gelu gate (div-free staging) ----------------
__global__ __launch_bounds__(256) void k_ffdw(const bf16_t* __restrict__ y,
                                              const float* __restrict__ w1,
                                              const float* __restrict__ w2,
                                              const float* __restrict__ w3,
                                              bf16_t* __restrict__ z) {
  __shared__ float lds[24 * 272];  // 26112 B
  int blk = blockIdx.x;
  int rq = blk & 63;
  int ch = (blk >> 6) % NHID;
  int b = blk / (NHID * 64);
  int yy0 = rq * 4;
  const bf16_t* yb = y + (size_t)(b * 288 + ch) * NP;
  // halo columns (x<0 and x>=256) are outside the image for every block -> zero
  if (threadIdx.x < 96) {
    int sr = threadIdx.x >> 2, part = threadIdx.x & 3;
    int slot = (part == 0) ? 0 : (256 + part * 4);  // 0 | 260 | 264 | 268
    *(float4*)(&lds[sr * 272 + slot]) = make_float4(0.f, 0.f, 0.f, 0.f);
  }
  // interior: 24 rows x 64 float4 groups; slot = x + 4
  #pragma unroll
  for (int it = 0; it < 6; ++it) {
    int sr = (threadIdx.x >> 6) + it * 4;
    int m = threadIdx.x & 63;
    int br, iy;
    if (sr < 6)       { br = 0; iy = yy0 + sr - 1; }
    else if (sr < 14) { br = 1; iy = yy0 + sr - 8; }
    else              { br = 2; iy = yy0 + sr - 17; }
    float4 v = make_float4(0.f, 0.f, 0.f, 0.f);
    if ((unsigned)iy < (unsigned)NH) {
      ushort4 u = *(const ushort4*)(yb + (size_t)(br * NHID) * NP + iy * NW + m * 4);
      v = make_float4(bf2f(u.x), bf2f(u.y), bf2f(u.z), bf2f(u.w));
    }
    *(float4*)(&lds[sr * 272 + 4 + m * 4]) = v;
  }
  __syncthreads();
  int q = threadIdx.x >> 6;
  int quad = threadIdx.x & 63;
  const float* wp1 = w1 + ch * 9;   // wave-uniform -> scalar loads
  const float* wp2 = w2 + ch * 9;
  const float* wp3 = w3 + ch * 9;
  float c1[4] = {0.f, 0.f, 0.f, 0.f};
  float c2[4] = {0.f, 0.f, 0.f, 0.f};
  float c3[4] = {0.f, 0.f, 0.f, 0.f};
  #pragma unroll
  for (int rr = 0; rr < 3; ++rr)
    STENCIL_ROW(0 + q + rr * 1, 1, wp1[rr * 3 + 0], wp1[rr * 3 + 1], wp1[rr * 3 + 2], c1);
  #pragma unroll
  for (int rr = 0; rr < 3; ++rr)
    STENCIL_ROW(6 + q + rr * 2, 2, wp2[rr * 3 + 0], wp2[rr * 3 + 1], wp2[rr * 3 + 2], c2);
  #pragma unroll
  for (int rr = 0; rr < 3; ++rr)
    STENCIL_ROW(14 + q + rr * 3, 3, wp3[rr * 3 + 0], wp3[rr * 3 + 1], wp3[rr * 3 + 2], c3);
  *(ushort4*)(z + (size_t)(b * NHID + ch) * NP + (yy0 + q) * NW + quad * 4) =
      make_ushort4(f2bf(gelu_f(c1[0]) * c2[0] * c3[0]),
                   f2bf(gelu_f(c1[1]) * c2[1] * c3[1]),
                   f2bf(gelu_f(c1[2]) * c2[2] * c3[2]),
                   f2bf(gelu_f(c1[3]) * c2[3] * c3[3]));
}

// ---------------- pout via MFMA (swapped operands): out[o][p] = x1[o][p] + (poutw @ z)[o][p] ----------------
__global__ __launch_bounds__(256) void k_pout_mfma(const bf16_t* __restrict__ z,
                                                   const bf16_t* __restrict__ WP,
                                                   const bf16_t* __restrict__ x1,
                                                   float* __restrict__ outp) {
  __shared__ bf16_t zT[64 * 104];  // 13312 B, row stride 104
  int blk = blockIdx.x;
  int pxt = blk & 1023;
  int b = blk >> 10;
  int pbase = pxt * 64;
  const bf16_t* zb = z + (size_t)b * NHID * NP + pbase;
  int p4 = threadIdx.x & 15, k0 = threadIdx.x >> 4;
  #pragma unroll
  for (int it = 0; it < 6; ++it) {
    int k = k0 + it * 16;
    ushort4 u = *(const ushort4*)(zb + (size_t)k * NP + p4 * 4);
    zT[(p4 * 4 + 0) * 104 + k] = u.x;
    zT[(p4 * 4 + 1) * 104 + k] = u.y;
    zT[(p4 * 4 + 2) * 104 + k] = u.z;
    zT[(p4 * 4 + 3) * 104 + k] = u.w;
  }
  __syncthreads();
  int w = threadIdx.x >> 6;
  int lane = threadIdx.x & 63;
  int prow = w * 16 + (lane & 15);
  bf16x8 bfr[3];
  #pragma unroll
  for (int s = 0; s < 3; ++s)
    bfr[s] = *(const bf16x8*)&zT[prow * 104 + s * 32 + ((lane >> 4) << 3)];
  int pg = w * 16 + ((lane >> 4) << 2);
  int p = pbase + pg;
  const bf16_t* x1b = x1 + (size_t)b * NC * NP + p;
  float* ob = outp + (size_t)b * NC * NP + p;
  #pragma unroll
  for (int ot = 0; ot < 3; ++ot) {
    f32x4 acc = {0.f, 0.f, 0.f, 0.f};
    #pragma unroll
    for (int s = 0; s < 3; ++s) {
      bf16x8 a = *(const bf16x8*)(WP + (size_t)(ot * 3 + s) * 512 + lane * 8);
      acc = __builtin_amdgcn_mfma_f32_16x16x32_bf16(bfr[s], a, acc, 0, 0, 0);
    }
    int o = ot * 16 + (lane & 15);
    ushort4 xv = *(const ushort4*)(x1b + (size_t)o * NP);
    float4 r;
    r.x = bf2f(xv.x) + acc[0];
    r.y = bf2f(xv.y) + acc[1];
    r.z = bf2f(xv.z) + acc[2];
    r.w = bf2f(xv.w) + acc[3];
    *(float4*)(ob + (size_t)o * NP) = r;
  }
}

// ---------------- workspace layout (float offsets; bf16 buffers use half) ----------------
constexpr size_t SZ_QKV = (size_t)NB * 144 * NP;
constexpr size_t SZ_CHW = (size_t)NB * NC * NP;
constexpr size_t OFF_QKV0 = 0;
constexpr size_t OFF_QKVD = OFF_QKV0 + SZ_QKV;         // bf16 buffers: region oversized, fine
constexpr size_t OFF_FCONV = OFF_QKVD + SZ_QKV;
constexpr size_t SZ_FCONV = (size_t)NB * 54 * NP;
constexpr size_t OFF_OUTCONV = OFF_FCONV + SZ_FCONV;
constexpr size_t OFF_X1 = OFF_OUTCONV + SZ_CHW;        // x1 bf16 (region oversized)
constexpr size_t OFF_STATS = OFF_X1 + SZ_CHW;          // repurposed: spart (512*48 <= NB*NP*2)
constexpr size_t OFF_T1 = OFF_STATS + (size_t)NB * NP * 2;  // t1 (conv, bf16) -> later SB/WA1/WA2/WP/WJ
constexpr size_t OFF_P1 = OFF_T1 + (size_t)NB * NC * 128 * 128;
constexpr size_t OFF_T2 = OFF_P1 + (size_t)NB * NC * 64 * 64;
constexpr size_t OFF_P2 = OFF_T2 + (size_t)NB * NC * 32 * 32;
constexpr size_t OFF_T3 = OFF_P2 + (size_t)NB * NC * 16 * 16;
constexpr size_t OFF_P3 = OFF_T3 + (size_t)NB * NC * 8 * 8;
constexpr size_t OFF_Q0M = OFF_P3 + (size_t)NB * NC * 4 * 4;
constexpr size_t OFF_NORMS = OFF_Q0M + 576;
constexpr size_t OFF_SPART = OFF_NORMS + 192;          // repurposed: A (576 floats)
constexpr size_t OFF_A = OFF_SPART + (size_t)NB * 64 * 48;

extern "C" void kernel_launch(void* const* d_in, const int* in_sizes, int n_in,
                              void* d_out, int out_size, void* d_ws, size_t ws_size,
                              hipStream_t stream) {
  const float* x     = (const float*)d_in[0];
  const float* ln1w  = (const float*)d_in[1];
  const float* ln1b  = (const float*)d_in[2];
  const float* qkvw  = (const float*)d_in[3];
  const float* qkvdw = (const float*)d_in[4];
  const float* projw = (const float*)d_in[5];
  const float* fcw   = (const float*)d_in[6];
  const float* fcb   = (const float*)d_in[7];
  const float* depw  = (const float*)d_in[8];
  const float* depb  = (const float*)d_in[9];
  const float* l2qw  = (const float*)d_in[10];
  const float* l2qb  = (const float*)d_in[11];
  const float* temp  = (const float*)d_in[12];
  const float* ln2w  = (const float*)d_in[13];
  const float* ln2b  = (const float*)d_in[14];
  const float* pinw  = (const float*)d_in[15];
  const float* dw1   = (const float*)d_in[16];
  const float* dw2   = (const float*)d_in[17];
  const float* dw3   = (const float*)d_in[18];
  const float* poutw = (const float*)d_in[19];
  const float* cvw0  = (const float*)d_in[20];
  const float* cvb0  = (const float*)d_in[21];
  const float* clw0  = (const float*)d_in[22];
  const float* clb0  = (const float*)d_in[23];
  const float* cvw1  = (const float*)d_in[24];
  const float* cvb1  = (const float*)d_in[25];
  const float* clw1  = (const float*)d_in[26];
  const float* clb1  = (const float*)d_in[27];
  const float* cvw2  = (const float*)d_in[28];
  const float* cvb2  = (const float*)d_in[29];
  const float* clw2  = (const float*)d_in[30];
  const float* clb2  = (const float*)d_in[31];

  float* ws = (float*)d_ws;
  bf16_t* qkv0 = (bf16_t*)(ws + OFF_QKV0);
  bf16_t* qkvd = (bf16_t*)(ws + OFF_QKVD);
  bf16_t* fconv = (bf16_t*)(ws + OFF_FCONV);
  bf16_t* outconv = (bf16_t*)(ws + OFF_OUTCONV);
  bf16_t* x1 = (bf16_t*)(ws + OFF_X1);
  bf16_t* t1b = (bf16_t*)(ws + OFF_T1);   // conv1 output, bf16
  float* p1 = ws + OFF_P1;
  float* t2 = ws + OFF_T2;
  float* p2 = ws + OFF_P2;
  float* t3 = ws + OFF_T3;
  float* p3 = ws + OFF_P3;
  float* q0m = ws + OFF_Q0M;
  float* spart = ws + OFF_STATS;      // 512*48 floats (fits 262144 region)
  float* A = ws + OFF_SPART;          // 576 floats
  // SB/WA1/WA2/WP/WJ live in the t1 region: t1 is dead after the first lnpool
  // and never touched again; k_prep runs after the conv branch (in-stream).
  float* SB = ws + OFF_T1;                                           // 864 floats
  bf16_t* WA1 = (bf16_t*)(ws + OFF_T1 + 1024);                       // 9216 bf16
  bf16_t* WA2 = (bf16_t*)(ws + OFF_T1 + 1024 + 4608);                // 18432 bf16
  bf16_t* WP  = (bf16_t*)(ws + OFF_T1 + 1024 + 4608 + 9216);         // 4608 bf16
  bf16_t* WJ  = (bf16_t*)(ws + OFF_T1 + 1024 + 4608 + 9216 + 2304);  // 3072 bf16
  // WC (conv1 fragments) lives in the qkv0 region: needed only during conv1,
  // which runs before anything writes qkv0 (k_chmix is after k_prep).
  bf16_t* WC = (bf16_t*)(ws + OFF_QKV0);                             // 27648 bf16
  bf16_t* ybuf = (bf16_t*)(ws + OFF_QKV0);   // reuse qkv0 region (bf16, fits)
  bf16_t* zbuf = (bf16_t*)(ws + OFF_FCONV);  // reuse fconv region (bf16, fits)

  // conv-descriptor branch: conv1 via MFMA (weights prepacked into dead region)
  k_prepw<<<108, 256, 0, stream>>>(cvw0, WC);
  k_conv1_mfma<<<512, 512, 0, stream>>>(x, WC, cvb0, t1b);
  k_lnpool_b<<<128, 256, 0, stream>>>(t1b, clw0, clb0, p1, 128, 128);
  k_conv_s2_tile<<<32, 512, 0, stream>>>(p1, cvw1, cvb1, t2, 64, 64, 32, 32);
  k_lnpool<<<8, 256, 0, stream>>>(t2, clw1, clb1, p2, 32, 32);
  k_conv_s2_tile<<<2, 512, 0, stream>>>(p2, cvw2, cvb2, t3, 16, 16, 8, 8);
  k_lnpool<<<1, 256, 0, stream>>>(t3, clw2, clb2, p3, 8, 8);
  k_head<<<2, 320, 0, stream>>>(p3, l2qw, l2qb, q0m);

  // LN folding + MFMA fragment packing (t1 region is dead by now)
  k_prep<<<8, 256, 0, stream>>>(qkvw, ln1w, ln1b, pinw, ln2w, ln2b, poutw, projw,
                                SB, WA1, WA2, WP, WJ);

  // attention
  k_chmix_mfma<<<NB * 1024, 256, 0, stream>>>(x, WA1, SB, SB + 144, qkv0, 144);
  k_dw144<<<NB * 144 * 32, 256, 0, stream>>>(qkv0, qkvdw, qkvd);
  k_gram<<<NB * NHEADS * GSEG, 256, 0, stream>>>(qkvd, spart);
  k_attn<<<2, 256, 0, stream>>>(spart, temp, q0m, A);
  k_fc<<<2048, 384, 0, stream>>>(qkvd, fcw, fcb, fconv);
  k_depconv<<<768, 256, 0, stream>>>(fconv, depw, depb, outconv);
  k_proj_mfma<<<NB * 1024, 256, 0, stream>>>(qkvd, A, WJ, x, outconv, x1);

  // feedforward
  k_chmix_mfma_b<<<NB * 1024, 256, 0, stream>>>(x1, WA2, SB + 288, SB + 576, ybuf, 288);
  k_ffdw<<<NB * NHID * 64, 256, 0, stream>>>(ybuf, dw1, dw2, dw3, zbuf);
  k_pout_mfma<<<NB * 1024, 256, 0, stream>>>(zbuf, WP, x1, (float*)d_out);
}

// Round 31
// 312.412 us; speedup vs baseline: 1.0323x; 1.0323x over previous
//
#include <hip/hip_runtime.h>

constexpr int NB = 2;
constexpr int NC = 48;
constexpr int NH = 256;
constexpr int NW = 256;
constexpr int NP = NH * NW;           // 65536
constexpr int NHEADS = 8;
constexpr int NCHD = 6;
constexpr int NHID = 96;
constexpr int GSEG = 32;              // gram segments per (b,h)

typedef unsigned short bf16_t;
typedef __attribute__((ext_vector_type(8))) short bf16x8;
typedef __attribute__((ext_vector_type(4))) float f32x4;

__device__ __forceinline__ float bf2f(bf16_t u) {
  union { unsigned int i; float f; } c; c.i = ((unsigned int)u) << 16; return c.f;
}
__device__ __forceinline__ bf16_t f2bf(float f) {
  union { float f; unsigned int i; } c; c.f = f;
  unsigned int r = (c.i + 0x7FFFu + ((c.i >> 16) & 1u)) >> 16;
  return (bf16_t)r;
}
__device__ __forceinline__ void unpack2(unsigned int u, float& a, float& b) {
  union { unsigned int i; float f; } c0, c1;
  c0.i = u << 16; c1.i = u & 0xffff0000u;
  a = c0.f; b = c1.f;
}

// tanh-form GELU via fast exp (max dev vs erf-form ~3e-4)
__device__ __forceinline__ float gelu_f(float v) {
  float u = v * (0.79788456f + 0.0356774081f * v * v);
  u = fminf(fmaxf(u, -9.f), 9.f);
  float e = __expf(-2.f * u);
  float th = (1.f - e) / (1.f + e);
  return 0.5f * v * (1.f + th);
}

// tap loop over a 12-float window (3x ds_read_b128), compile-time indices.
#define STENCIL_ROW(LROW, D, WVAL0, WVAL1, WVAL2, ACC)                        \
  {                                                                            \
    const float* lp = &lds[(LROW) * 272 + quad * 4];                           \
    float4 va = *(const float4*)lp;                                            \
    float4 vb = *(const float4*)(lp + 4);                                      \
    float4 vc = *(const float4*)(lp + 8);                                      \
    float v[12] = {va.x, va.y, va.z, va.w, vb.x, vb.y, vb.z, vb.w,             \
                   vc.x, vc.y, vc.z, vc.w};                                    \
    _Pragma("unroll") for (int jj = 0; jj < 4; ++jj) {                         \
      ACC[jj] = fmaf(v[jj - (D) + 4], WVAL0, ACC[jj]);                         \
      ACC[jj] = fmaf(v[jj + 4], WVAL1, ACC[jj]);                               \
      ACC[jj] = fmaf(v[jj + (D) + 4], WVAL2, ACC[jj]);                         \
    }                                                                          \
  }

// ---------------- conv1 weight prepack: per-tap MFMA A-fragments ----------------
__global__ void k_prepw(const float* __restrict__ cvw0, bf16_t* __restrict__ WC) {
  int i = blockIdx.x * blockDim.x + threadIdx.x;
  if (i >= 9 * 3 * 2 * 512) return;
  int j = i & 7, lane = (i >> 3) & 63;
  int fi = i >> 9;
  int s = fi & 1;
  int tot = fi >> 1;
  int ot = tot % 3, t = tot / 3;
  int o = ot * 16 + (lane & 15);
  int k = s * 32 + ((lane >> 4) << 3) + j;
  float v = (k < 48) ? cvw0[(size_t)(o * 48 + k) * 9 + t] : 0.f;
  WC[i] = f2bf(v);
}

// ---------------- conv1 via MFMA: 8x8 out tile, split-K, vectorized interior staging ----------------
__global__ __launch_bounds__(512) void k_conv1_mfma(const float* __restrict__ in,
                                                    const bf16_t* __restrict__ WC,
                                                    const float* __restrict__ bias,
                                                    bf16_t* __restrict__ out) {
  __shared__ bf16_t xs[17 * 17 * 72];   // 41616 B, [iy][ix][ic] ic-stride 72
  __shared__ float red[4 * 3 * 64 * 4]; // 12288 B split-K partials
  int blk = blockIdx.x;
  int tx = blk & 15;
  int t0 = blk >> 4;
  int ty = t0 & 15, b = t0 >> 4;
  int oy0 = ty * 8, ox0 = tx * 8;
  int iy0 = oy0 * 2 - 1, ix0 = ox0 * 2 - 1;
  const float* inb = in + (size_t)b * NC * NP;
  if (tx > 0 && ty > 0) {
    // interior: rows fully in-bounds; 5 aligned float4 per 17-wide row
    int bx = ix0 - 3;  // byte offset 16*(4*tx-1) -> 16B aligned
    for (int v = threadIdx.x; v < 48 * 17 * 5; v += 512) {
      int part = v % 5;
      int row = v / 5;
      int rr = row % 17;
      int ic = row / 17;
      const float* src = inb + ((size_t)ic << 16) + ((size_t)(iy0 + rr) << 8) + bx + part * 4;
      float4 f = *(const float4*)src;
      float fv[4] = {f.x, f.y, f.z, f.w};
      int cc0 = part * 4 - 3;
      #pragma unroll
      for (int e = 0; e < 4; ++e) {
        int cc = cc0 + e;
        if ((unsigned)cc < 17u) xs[(rr * 17 + cc) * 72 + ic] = f2bf(fv[e]);
      }
    }
  } else {
    for (int i = threadIdx.x; i < 17 * 17 * 48; i += 512) {
      int cc = i % 17;
      int t2 = i / 17;
      int rr = t2 % 17;
      int ic = t2 / 17;
      float v = 0.f;
      int iy = iy0 + rr, ix = ix0 + cc;
      if ((unsigned)iy < 256u && (unsigned)ix < 256u)
        v = inb[((size_t)ic << 16) + (iy << 8) + ix];
      xs[(rr * 17 + cc) * 72 + ic] = f2bf(v);
    }
  }
  for (int i = threadIdx.x; i < 289 * 16; i += 512) {  // zero-pad k 48..63
    int rcc = i >> 4, icz = i & 15;
    xs[rcc * 72 + 48 + icz] = 0;
  }
  __syncthreads();
  int wid = threadIdx.x >> 6, lane = threadIdx.x & 63;
  int pt = wid & 3, s = wid >> 2;
  int l15 = lane & 15, kl = lane >> 4;
  int px = pt * 16 + l15;
  int oy = px >> 3, ox = px & 7;
  int base = ((oy * 2) * 17 + ox * 2) * 72 + s * 32 + kl * 8;
  f32x4 acc[3] = {{0.f, 0.f, 0.f, 0.f}, {0.f, 0.f, 0.f, 0.f}, {0.f, 0.f, 0.f, 0.f}};
  #pragma unroll
  for (int t = 0; t < 9; ++t) {
    int dy = t / 3, dx = t % 3;  // compile-time
    bf16x8 bf = *(const bf16x8*)&xs[base + dy * (17 * 72) + dx * 72];
    #pragma unroll
    for (int ot = 0; ot < 3; ++ot) {
      bf16x8 af = *(const bf16x8*)(WC + (size_t)((t * 3 + ot) * 2 + s) * 512 + lane * 8);
      acc[ot] = __builtin_amdgcn_mfma_f32_16x16x32_bf16(af, bf, acc[ot], 0, 0, 0);
    }
  }
  if (s == 1) {
    #pragma unroll
    for (int ot = 0; ot < 3; ++ot)
      #pragma unroll
      for (int j = 0; j < 4; ++j)
        red[((pt * 3 + ot) * 64 + lane) * 4 + j] = acc[ot][j];
  }
  __syncthreads();
  if (s == 0) {
    bf16_t* ob = out + (size_t)b * NC * 16384;
    #pragma unroll
    for (int ot = 0; ot < 3; ++ot) {
      #pragma unroll
      for (int j = 0; j < 4; ++j) {
        int o = ot * 16 + kl * 4 + j;
        float r = acc[ot][j] + red[((pt * 3 + ot) * 64 + lane) * 4 + j] + bias[o];
        ob[((size_t)o * 128 + oy0 + oy) * 128 + ox0 + ox] = f2bf(r);
      }
    }
  }
}

// ---------------- conv-descriptor branch (conv2/conv3): ic-chunked, 8-wave blocks ----------------
__global__ __launch_bounds__(512) void k_conv_s2_tile(const float* __restrict__ in,
                                                      const float* __restrict__ w,
                                                      const float* __restrict__ bias,
                                                      float* __restrict__ out,
                                                      int IH, int IW, int OH, int OW) {
  __shared__ float lds[16 * 442];  // 16 ic * 17 rows * 26 = 28288 B
  int tilesX = OW >> 3;
  int tilesY = OH >> 3;
  int blk = blockIdx.x;
  int tx = blk % tilesX;
  int t = blk / tilesX;
  int ty = t % tilesY;
  int b = t / tilesY;
  int oy0 = ty * 8, ox0 = tx * 8;
  int iy0 = oy0 * 2 - 1, ix0 = ox0 * 2 - 1;
  const float* inb = in + (size_t)b * NC * IH * IW;

  int lane = threadIdx.x & 63;
  int oy = lane >> 3, ox = lane & 7;
  int ocb = __builtin_amdgcn_readfirstlane((threadIdx.x >> 6) * 6);
  float acc[6];
  #pragma unroll
  for (int j = 0; j < 6; ++j) acc[j] = bias[ocb + j];
  int rbase = oy * 52;  // row 2*oy, stride 26

  for (int chunk = 0; chunk < 3; ++chunk) {
    int icb = chunk * 16;
    for (int i = threadIdx.x; i < 16 * 17 * 17; i += 512) {
      int cc = i % 17;
      int t2 = i / 17;
      int rr = t2 % 17;
      int ic = t2 / 17;
      float v = 0.f;
      int iy = iy0 + rr, ix = ix0 + cc;
      if ((unsigned)iy < (unsigned)IH && (unsigned)ix < (unsigned)IW)
        v = inb[((size_t)(icb + ic) * IH + iy) * IW + ix];
      lds[ic * 442 + rr * 26 + ((cc & 1) ? 13 + (cc >> 1) : (cc >> 1))] = v;
    }
    __syncthreads();

    for (int ic16 = 0; ic16 < 16; ++ic16) {
      const float* base = lds + ic16 * 442 + rbase;
      float e0[3], e1[3], ov[3];
      #pragma unroll
      for (int ky = 0; ky < 3; ++ky) {
        const float* rowp = base + ky * 26;
        e0[ky] = rowp[ox];
        e1[ky] = rowp[ox + 1];
        ov[ky] = rowp[13 + ox];
      }
      const float* wpc = w + (size_t)(ocb * 48 + icb + ic16) * 9;
      #pragma unroll
      for (int j = 0; j < 6; ++j) {
        const float* wp = wpc + (size_t)j * 48 * 9;
        float a = acc[j];
        #pragma unroll
        for (int ky = 0; ky < 3; ++ky) {
          a = fmaf(wp[ky * 3 + 0], e0[ky], a);
          a = fmaf(wp[ky * 3 + 1], ov[ky], a);
          a = fmaf(wp[ky * 3 + 2], e1[ky], a);
        }
        acc[j] = a;
      }
    }
    __syncthreads();
  }

  float* ob = out + (size_t)b * NC * OH * OW;
  #pragma unroll
  for (int j = 0; j < 6; ++j)
    ob[((size_t)(ocb + j) * OH + oy0 + oy) * OW + ox0 + ox] = acc[j];
}

// ---------------- lnpool (f32 input): 4 sublanes share the channel loop ----------------
__global__ void k_lnpool(const float* __restrict__ in, const float* __restrict__ lw,
                         const float* __restrict__ lb, float* __restrict__ out,
                         int IH, int IW) {
  int OH = IH >> 1, OW = IW >> 1;
  int tid = blockIdx.x * blockDim.x + threadIdx.x;
  int idx = tid >> 2;
  int sl = tid & 3;        // channels sl*12 .. sl*12+11
  int total = NB * OH * OW;
  if (idx >= total) return;
  int ox = idx % OW;
  int t = idx / OW;
  int oy = t % OH;
  int b = t / OH;
  const float* inb = in + (size_t)b * NC * IH * IW;
  float vq[12][4];
  float s[4] = {0.f, 0.f, 0.f, 0.f}, ss[4] = {0.f, 0.f, 0.f, 0.f};
  #pragma unroll
  for (int cl = 0; cl < 12; ++cl) {
    int c = sl * 12 + cl;
    #pragma unroll
    for (int q = 0; q < 4; ++q) {
      int iy = oy * 2 + (q >> 1), ix = ox * 2 + (q & 1);
      float v = inb[((size_t)c * IH + iy) * IW + ix];
      vq[cl][q] = v;
      s[q] += v;
      ss[q] = fmaf(v, v, ss[q]);
    }
  }
  #pragma unroll
  for (int q = 0; q < 4; ++q) {
    s[q] += __shfl_xor(s[q], 1, 64);
    s[q] += __shfl_xor(s[q], 2, 64);
    ss[q] += __shfl_xor(ss[q], 1, 64);
    ss[q] += __shfl_xor(ss[q], 2, 64);
  }
  float mu[4], rs[4];
  #pragma unroll
  for (int q = 0; q < 4; ++q) {
    float m = s[q] * (1.f / NC);
    mu[q] = m;
    rs[q] = rsqrtf(fmaxf(ss[q] * (1.f / NC) - m * m, 0.f) + 1e-5f);
  }
  #pragma unroll
  for (int cl = 0; cl < 12; ++cl) {
    int c = sl * 12 + cl;
    float wv = lw[c], bv = lb[c];
    float best = 0.f;  // relu >= 0 so 0 == max of relu'd window
    #pragma unroll
    for (int q = 0; q < 4; ++q) {
      float v = (vq[cl][q] - mu[q]) * rs[q] * wv + bv;
      best = fmaxf(best, fmaxf(v, 0.f));
    }
    out[((size_t)(b * NC + c) * OH + oy) * OW + ox] = best;
  }
}

// ---------------- lnpool (bf16 input, stage 1) ----------------
__global__ void k_lnpool_b(const bf16_t* __restrict__ in, const float* __restrict__ lw,
                           const float* __restrict__ lb, float* __restrict__ out,
                           int IH, int IW) {
  int OH = IH >> 1, OW = IW >> 1;
  int tid = blockIdx.x * blockDim.x + threadIdx.x;
  int idx = tid >> 2;
  int sl = tid & 3;        // channels sl*12 .. sl*12+11
  int total = NB * OH * OW;
  if (idx >= total) return;
  int ox = idx % OW;
  int t = idx / OW;
  int oy = t % OH;
  int b = t / OH;
  const bf16_t* inb = in + (size_t)b * NC * IH * IW;
  float vq[12][4];
  float s[4] = {0.f, 0.f, 0.f, 0.f}, ss[4] = {0.f, 0.f, 0.f, 0.f};
  #pragma unroll
  for (int cl = 0; cl < 12; ++cl) {
    int c = sl * 12 + cl;
    #pragma unroll
    for (int q = 0; q < 4; ++q) {
      int iy = oy * 2 + (q >> 1), ix = ox * 2 + (q & 1);
      float v = bf2f(inb[((size_t)c * IH + iy) * IW + ix]);
      vq[cl][q] = v;
      s[q] += v;
      ss[q] = fmaf(v, v, ss[q]);
    }
  }
  #pragma unroll
  for (int q = 0; q < 4; ++q) {
    s[q] += __shfl_xor(s[q], 1, 64);
    s[q] += __shfl_xor(s[q], 2, 64);
    ss[q] += __shfl_xor(ss[q], 1, 64);
    ss[q] += __shfl_xor(ss[q], 2, 64);
  }
  float mu[4], rs[4];
  #pragma unroll
  for (int q = 0; q < 4; ++q) {
    float m = s[q] * (1.f / NC);
    mu[q] = m;
    rs[q] = rsqrtf(fmaxf(ss[q] * (1.f / NC) - m * m, 0.f) + 1e-5f);
  }
  #pragma unroll
  for (int cl = 0; cl < 12; ++cl) {
    int c = sl * 12 + cl;
    float wv = lw[c], bv = lb[c];
    float best = 0.f;
    #pragma unroll
    for (int q = 0; q < 4; ++q) {
      float v = (vq[cl][q] - mu[q]) * rs[q] * wv + bv;
      best = fmaxf(best, fmaxf(v, 0.f));
    }
    out[((size_t)(b * NC + c) * OH + oy) * OW + ox] = best;
  }
}

__global__ void k_head(const float* __restrict__ p3, const float* __restrict__ l2qw,
                       const float* __restrict__ l2qb, float* __restrict__ q0m) {
  __shared__ float xd[NC], q0[NC];
  int b = blockIdx.x, t = threadIdx.x;
  if (t < NC) {
    float s = 0.f;
    for (int i = 0; i < 16; ++i) s += p3[(b * NC + t) * 16 + i];
    xd[t] = gelu_f(s * (1.f / 16.f));
  }
  __syncthreads();
  if (t < NC) {
    float a = l2qb[t];
    for (int c = 0; c < NC; ++c) a += xd[c] * l2qw[t * NC + c];
    q0[t] = a;
  }
  __syncthreads();
  if (t < NHEADS * NCHD * NCHD) {
    int h = t / 36, r = t % 36, c = r / 6, d = r % 6;
    q0m[b * 288 + t] = q0[h * 6 + c] * q0[h * 6 + d];
  }
}

// ---------------- prep: S/B vectors + bf16 A-fragment-packed weights (qkv, pin, pout, proj) ----------------
__global__ void k_prep(const float* __restrict__ qkvw, const float* __restrict__ ln1w,
                       const float* __restrict__ ln1b, const float* __restrict__ pinw,
                       const float* __restrict__ ln2w, const float* __restrict__ ln2b,
                       const float* __restrict__ poutw, const float* __restrict__ projw,
                       float* __restrict__ SB, bf16_t* __restrict__ WA1,
                       bf16_t* __restrict__ WA2, bf16_t* __restrict__ WP,
                       bf16_t* __restrict__ WJ) {
  int t = blockIdx.x * blockDim.x + threadIdx.x;
  int stride = gridDim.x * blockDim.x;
  if (t < 144) {
    float s = 0.f, bb = 0.f;
    for (int c = 0; c < 48; ++c) {
      float w = qkvw[t * 48 + c];
      s = fmaf(w, ln1w[c], s); bb = fmaf(w, ln1b[c], bb);
    }
    SB[t] = s; SB[144 + t] = bb;
  } else if (t < 144 + 288) {
    int o = t - 144;
    float s = 0.f, bb = 0.f;
    for (int c = 0; c < 48; ++c) {
      float w = pinw[o * 48 + c];
      s = fmaf(w, ln2w[c], s); bb = fmaf(w, ln2b[c], bb);
    }
    SB[288 + o] = s; SB[576 + o] = bb;
  }
  for (int i = t; i < 9 * 1024; i += stride) {   // 144 oc: 9 ot * 2 s * 64 lane * 8 j
    int j = i & 7, lane = (i >> 3) & 63, s = (i >> 9) & 1, ot = i >> 10;
    int o = ot * 16 + (lane & 15);
    int k = s * 32 + ((lane >> 4) << 3) + j;
    float v = (k < 48) ? qkvw[o * 48 + k] * ln1w[k] : 0.f;
    WA1[i] = f2bf(v);
  }
  for (int i = t; i < 18 * 1024; i += stride) {  // 288 oc: 18 ot
    int j = i & 7, lane = (i >> 3) & 63, s = (i >> 9) & 1, ot = i >> 10;
    int o = ot * 16 + (lane & 15);
    int k = s * 32 + ((lane >> 4) << 3) + j;
    float v = (k < 48) ? pinw[o * 48 + k] * ln2w[k] : 0.f;
    WA2[i] = f2bf(v);
  }
  for (int i = t; i < 9 * 512; i += stride) {    // pout: 3 ot * 3 s * 512
    int j = i & 7, lane = (i >> 3) & 63;
    int fi = i >> 9;
    int s = fi % 3, ot = fi / 3;
    int o = ot * 16 + (lane & 15);
    int k = s * 32 + ((lane >> 4) << 3) + j;
    WP[i] = f2bf(poutw[o * 96 + k]);
  }
  for (int i = t; i < 6 * 512; i += stride) {    // proj: 3 ot * 2 s * 512
    int j = i & 7, lane = (i >> 3) & 63;
    int fi = i >> 9;
    int s = fi & 1, ot = fi >> 1;
    int o = ot * 16 + (lane & 15);
    int k = s * 32 + ((lane >> 4) << 3) + j;
    float v = (k < 48) ? projw[o * 48 + k] : 0.f;
    WJ[i] = f2bf(v);
  }
}

// ---------------- channel-mix via MFMA: 64-px tile, bf16 fragments (f32 input) ----------------
// out[o][p] = rstd[p]*(mfma(W',xT)[o][p] - mu[p]*S[o]) + B[o]
__global__ __launch_bounds__(256) void k_chmix_mfma(const float* __restrict__ x,
                                                    const bf16_t* __restrict__ WA,
                                                    const float* __restrict__ S,
                                                    const float* __restrict__ Bc,
                                                    bf16_t* __restrict__ out,
                                                    int nout) {
  __shared__ bf16_t xT[64 * 72];       // 9216 B, row stride 72 (2-way bank alias)
  __shared__ float smu[64], srstd[64];
  int blk = blockIdx.x;
  int pxt = blk & 1023;
  int b = blk >> 10;
  int pbase = pxt * 64;
  const float* xb = x + (size_t)b * NC * NP + pbase;
  int p4 = threadIdx.x & 15, k0 = threadIdx.x >> 4;
  #pragma unroll
  for (int it = 0; it < 3; ++it) {
    int k = k0 + it * 16;
    float4 v = *(const float4*)(xb + (size_t)k * NP + p4 * 4);
    xT[(p4 * 4 + 0) * 72 + k] = f2bf(v.x);
    xT[(p4 * 4 + 1) * 72 + k] = f2bf(v.y);
    xT[(p4 * 4 + 2) * 72 + k] = f2bf(v.z);
    xT[(p4 * 4 + 3) * 72 + k] = f2bf(v.w);
  }
  {  // zero-pad k = 48..63
    int k = 48 + k0;
    xT[(p4 * 4 + 0) * 72 + k] = 0;
    xT[(p4 * 4 + 1) * 72 + k] = 0;
    xT[(p4 * 4 + 2) * 72 + k] = 0;
    xT[(p4 * 4 + 3) * 72 + k] = 0;
  }
  __syncthreads();
  if (threadIdx.x < 64) {
    int t = threadIdx.x;
    float s = 0.f, ss = 0.f;
    #pragma unroll
    for (int k4 = 0; k4 < 12; ++k4) {
      ushort4 u = *(const ushort4*)&xT[t * 72 + k4 * 4];
      float a0 = bf2f(u.x), a1 = bf2f(u.y), a2 = bf2f(u.z), a3 = bf2f(u.w);
      s += a0 + a1 + a2 + a3;
      ss = fmaf(a0, a0, ss); ss = fmaf(a1, a1, ss);
      ss = fmaf(a2, a2, ss); ss = fmaf(a3, a3, ss);
    }
    float mu = s * (1.f / NC);
    smu[t] = mu;
    srstd[t] = rsqrtf(fmaxf(ss * (1.f / NC) - mu * mu, 0.f) + 1e-5f);
  }
  int w = threadIdx.x >> 6;
  int lane = threadIdx.x & 63;
  bf16x8 bfr0 = *(const bf16x8*)&xT[(w * 16 + (lane & 15)) * 72 + ((lane >> 4) << 3)];
  bf16x8 bfr1 = *(const bf16x8*)&xT[(w * 16 + (lane & 15)) * 72 + 32 + ((lane >> 4) << 3)];
  __syncthreads();
  float mu = smu[w * 16 + (lane & 15)];
  float rs = srstd[w * 16 + (lane & 15)];
  int p = pbase + w * 16 + (lane & 15);
  int nt = nout >> 4;
  bf16_t* ob = out + (size_t)b * nout * NP + p;
  for (int ot = 0; ot < nt; ++ot) {
    bf16x8 a0 = *(const bf16x8*)(WA + (size_t)(ot * 2 + 0) * 512 + lane * 8);
    bf16x8 a1 = *(const bf16x8*)(WA + (size_t)(ot * 2 + 1) * 512 + lane * 8);
    f32x4 acc = {0.f, 0.f, 0.f, 0.f};
    acc = __builtin_amdgcn_mfma_f32_16x16x32_bf16(a0, bfr0, acc, 0, 0, 0);
    acc = __builtin_amdgcn_mfma_f32_16x16x32_bf16(a1, bfr1, acc, 0, 0, 0);
    int orow = ot * 16 + ((lane >> 4) << 2);
    #pragma unroll
    for (int j = 0; j < 4; ++j) {
      int o = orow + j;
      float r = fmaf(rs, acc[j] - mu * S[o], Bc[o]);
      ob[(size_t)o * NP] = f2bf(r);
    }
  }
}

// ---------------- channel-mix via MFMA, bf16 input (for x1) ----------------
__global__ __launch_bounds__(256) void k_chmix_mfma_b(const bf16_t* __restrict__ x,
                                                      const bf16_t* __restrict__ WA,
                                                      const float* __restrict__ S,
                                                      const float* __restrict__ Bc,
                                                      bf16_t* __restrict__ out,
                                                      int nout) {
  __shared__ bf16_t xT[64 * 72];
  __shared__ float smu[64], srstd[64];
  int blk = blockIdx.x;
  int pxt = blk & 1023;
  int b = blk >> 10;
  int pbase = pxt * 64;
  const bf16_t* xb = x + (size_t)b * NC * NP + pbase;
  int p4 = threadIdx.x & 15, k0 = threadIdx.x >> 4;
  #pragma unroll
  for (int it = 0; it < 3; ++it) {
    int k = k0 + it * 16;
    ushort4 u = *(const ushort4*)(xb + (size_t)k * NP + p4 * 4);
    xT[(p4 * 4 + 0) * 72 + k] = u.x;
    xT[(p4 * 4 + 1) * 72 + k] = u.y;
    xT[(p4 * 4 + 2) * 72 + k] = u.z;
    xT[(p4 * 4 + 3) * 72 + k] = u.w;
  }
  {  // zero-pad k = 48..63
    int k = 48 + k0;
    xT[(p4 * 4 + 0) * 72 + k] = 0;
    xT[(p4 * 4 + 1) * 72 + k] = 0;
    xT[(p4 * 4 + 2) * 72 + k] = 0;
    xT[(p4 * 4 + 3) * 72 + k] = 0;
  }
  __syncthreads();
  if (threadIdx.x < 64) {
    int t = threadIdx.x;
    float s = 0.f, ss = 0.f;
    #pragma unroll
    for (int k4 = 0; k4 < 12; ++k4) {
      ushort4 u = *(const ushort4*)&xT[t * 72 + k4 * 4];
      float a0 = bf2f(u.x), a1 = bf2f(u.y), a2 = bf2f(u.z), a3 = bf2f(u.w);
      s += a0 + a1 + a2 + a3;
      ss = fmaf(a0, a0, ss); ss = fmaf(a1, a1, ss);
      ss = fmaf(a2, a2, ss); ss = fmaf(a3, a3, ss);
    }
    float mu = s * (1.f / NC);
    smu[t] = mu;
    srstd[t] = rsqrtf(fmaxf(ss * (1.f / NC) - mu * mu, 0.f) + 1e-5f);
  }
  int w = threadIdx.x >> 6;
  int lane = threadIdx.x & 63;
  bf16x8 bfr0 = *(const bf16x8*)&xT[(w * 16 + (lane & 15)) * 72 + ((lane >> 4) << 3)];
  bf16x8 bfr1 = *(const bf16x8*)&xT[(w * 16 + (lane & 15)) * 72 + 32 + ((lane >> 4) << 3)];
  __syncthreads();
  float mu = smu[w * 16 + (lane & 15)];
  float rs = srstd[w * 16 + (lane & 15)];
  int p = pbase + w * 16 + (lane & 15);
  int nt = nout >> 4;
  bf16_t* ob = out + (size_t)b * nout * NP + p;
  for (int ot = 0; ot < nt; ++ot) {
    bf16x8 a0 = *(const bf16x8*)(WA + (size_t)(ot * 2 + 0) * 512 + lane * 8);
    bf16x8 a1 = *(const bf16x8*)(WA + (size_t)(ot * 2 + 1) * 512 + lane * 8);
    f32x4 acc = {0.f, 0.f, 0.f, 0.f};
    acc = __builtin_amdgcn_mfma_f32_16x16x32_bf16(a0, bfr0, acc, 0, 0, 0);
    acc = __builtin_amdgcn_mfma_f32_16x16x32_bf16(a1, bfr1, acc, 0, 0, 0);
    int orow = ot * 16 + ((lane >> 4) << 2);
    #pragma unroll
    for (int j = 0; j < 4; ++j) {
      int o = orow + j;
      float r = fmaf(rs, acc[j] - mu * S[o], Bc[o]);
      ob[(size_t)o * NP] = f2bf(r);
    }
  }
}

// ---------------- depthwise 3x3 on 144 channels (8-row stripe, bf16 in/out) ----------------
__global__ __launch_bounds__(256) void k_dw144(const bf16_t* __restrict__ in,
                                               const float* __restrict__ w9,
                                               bf16_t* __restrict__ out) {
  __shared__ float lds[10 * 272];  // 10880 B
  int blk = blockIdx.x;
  int rq = blk & 31;
  int ch = (blk >> 5) % 144;
  int b = blk / (144 * 32);
  int yy0 = rq * 8;
  const bf16_t* ib = in + (size_t)(b * 144 + ch) * NP;
  if (threadIdx.x < 40) {  // x-halo zeros: 10 rows x {slot0, 260,264,268}
    int sr = threadIdx.x >> 2, part = threadIdx.x & 3;
    int slot = (part == 0) ? 0 : (256 + part * 4);
    *(float4*)(&lds[sr * 272 + slot]) = make_float4(0.f, 0.f, 0.f, 0.f);
  }
  for (int i = threadIdx.x; i < 640; i += 256) {  // 10 rows x 64 float4 groups
    int sr = i >> 6, m = i & 63;
    int iy = yy0 + sr - 1;
    float4 v = make_float4(0.f, 0.f, 0.f, 0.f);
    if ((unsigned)iy < (unsigned)NH) {
      ushort4 u = *(const ushort4*)(ib + iy * NW + m * 4);
      v = make_float4(bf2f(u.x), bf2f(u.y), bf2f(u.z), bf2f(u.w));
    }
    *(float4*)(&lds[sr * 272 + 4 + m * 4]) = v;
  }
  __syncthreads();
  int q = threadIdx.x >> 6;
  int quad = threadIdx.x & 63;
  const float* wp = w9 + ch * 9;   // wave-uniform -> scalar loads
  bf16_t* ob = out + (size_t)(b * 144 + ch) * NP;
  #pragma unroll
  for (int half = 0; half < 2; ++half) {
    int orow = q + half * 4;
    float acc[4] = {0.f, 0.f, 0.f, 0.f};
    #pragma unroll
    for (int rr = 0; rr < 3; ++rr)
      STENCIL_ROW(orow + rr, 1, wp[rr * 3 + 0], wp[rr * 3 + 1], wp[rr * 3 + 2], acc);
    *(ushort4*)(ob + (yy0 + orow) * NW + quad * 4) =
        make_ushort4(f2bf(acc[0]), f2bf(acc[1]), f2bf(acc[2]), f2bf(acc[3]));
  }
}

// ---------------- per-head Gram (36) + channel ssq (12), GSEG=32, split-butterfly reduce ----------------
__global__ __launch_bounds__(256) void k_gram(const bf16_t* __restrict__ qkvd,
                                              float* __restrict__ spart) {
  int gid = blockIdx.x;  // b*256 + h*32 + seg
  int seg = gid & (GSEG - 1), h = (gid >> 5) & 7, b = gid >> 8;
  const bf16_t* qb = qkvd + (size_t)(b * 144 + h * 6) * NP;
  const bf16_t* kb = qkvd + (size_t)(b * 144 + 48 + h * 6) * NP;
  float acc[48];
  #pragma unroll
  for (int j = 0; j < 48; ++j) acc[j] = 0.f;
  #pragma unroll
  for (int it = 0; it < 2; ++it) {
    int p0 = seg * (NP / GSEG) + it * 1024 + threadIdx.x * 4;
    float qv[6][4], kv[6][4];
    #pragma unroll
    for (int c = 0; c < 6; ++c) {
      ushort4 uq = *(const ushort4*)(qb + (size_t)c * NP + p0);
      qv[c][0] = bf2f(uq.x); qv[c][1] = bf2f(uq.y); qv[c][2] = bf2f(uq.z); qv[c][3] = bf2f(uq.w);
      ushort4 uk = *(const ushort4*)(kb + (size_t)c * NP + p0);
      kv[c][0] = bf2f(uk.x); kv[c][1] = bf2f(uk.y); kv[c][2] = bf2f(uk.z); kv[c][3] = bf2f(uk.w);
    }
    #pragma unroll
    for (int px = 0; px < 4; ++px) {
      #pragma unroll
      for (int c = 0; c < 6; ++c)
        #pragma unroll
        for (int d = 0; d < 6; ++d)
          acc[c * 6 + d] = fmaf(qv[c][px], kv[d][px], acc[c * 6 + d]);
      #pragma unroll
      for (int c = 0; c < 6; ++c) acc[36 + c] = fmaf(qv[c][px], qv[c][px], acc[36 + c]);
      #pragma unroll
      for (int d = 0; d < 6; ++d) acc[42 + d] = fmaf(kv[d][px], kv[d][px], acc[42 + d]);
    }
  }
  int lane = threadIdx.x & 63, wid = threadIdx.x >> 6;
  // split-butterfly: halve the j-set at each xor step (compile-time indices)
  bool h1 = (lane & 32) != 0;
  float r1[24];
  #pragma unroll
  for (int m = 0; m < 24; ++m) {
    float keep = h1 ? acc[m + 24] : acc[m];
    float send = h1 ? acc[m] : acc[m + 24];
    r1[m] = keep + __shfl_xor(send, 32, 64);
  }
  bool h2 = (lane & 16) != 0;
  float r2[12];
  #pragma unroll
  for (int m = 0; m < 12; ++m) {
    float keep = h2 ? r1[m + 12] : r1[m];
    float send = h2 ? r1[m] : r1[m + 12];
    r2[m] = keep + __shfl_xor(send, 16, 64);
  }
  bool h3 = (lane & 8) != 0;
  float r3[6];
  #pragma unroll
  for (int m = 0; m < 6; ++m) {
    float keep = h3 ? r2[m + 6] : r2[m];
    float send = h3 ? r2[m] : r2[m + 6];
    r3[m] = keep + __shfl_xor(send, 8, 64);
  }
  bool h4 = (lane & 4) != 0;
  float r4[3];
  #pragma unroll
  for (int m = 0; m < 3; ++m) {
    float keep = h4 ? r3[m + 3] : r3[m];
    float send = h4 ? r3[m] : r3[m + 3];
    r4[m] = keep + __shfl_xor(send, 4, 64);
    r4[m] += __shfl_xor(r4[m], 2, 64);
    r4[m] += __shfl_xor(r4[m], 1, 64);
  }
  int jb = (h1 ? 24 : 0) + (h2 ? 12 : 0) + (h3 ? 6 : 0) + (h4 ? 3 : 0);
  __shared__ float sr[4 * 48];
  if ((lane & 3) == 0) {
    #pragma unroll
    for (int m = 0; m < 3; ++m) sr[wid * 48 + jb + m] = r4[m];
  }
  __syncthreads();
  if (threadIdx.x < 48)
    spart[(size_t)gid * 48 + threadIdx.x] =
        sr[threadIdx.x] + sr[48 + threadIdx.x] + sr[96 + threadIdx.x] + sr[144 + threadIdx.x];
}

// ---------------- attention softmax (cooperative seg reduce + softmax) ----------------
__global__ __launch_bounds__(256) void k_attn(const float* __restrict__ spart,
                                              const float* __restrict__ temp,
                                              const float* __restrict__ q0m,
                                              float* __restrict__ A) {
  int b = blockIdx.x;
  __shared__ float tot[8 * 48];
  for (int j = threadIdx.x; j < 384; j += 256) {
    int h = j / 48, v = j % 48;
    const float* base = spart + ((size_t)(b * 8 + h) * GSEG) * 48 + v;
    float s = 0.f;
    for (int seg = 0; seg < GSEG; ++seg) s += base[(size_t)seg * 48];
    tot[j] = s;
  }
  __syncthreads();
  int t = threadIdx.x;
  if (t >= 48) return;
  int h = t / 6, c = t % 6;
  const float* T = &tot[h * 48];
  float nq = fmaxf(sqrtf(T[36 + c]), 1e-12f);
  float tm = temp[h];
  float lg[6];
  #pragma unroll
  for (int d = 0; d < 6; ++d) {
    float nk = fmaxf(sqrtf(T[42 + d]), 1e-12f);
    lg[d] = (T[c * 6 + d] / (nq * nk)) * tm * q0m[b * 288 + h * 36 + c * 6 + d];
  }
  float m = lg[0];
  #pragma unroll
  for (int d = 1; d < 6; ++d) m = fmaxf(m, lg[d]);
  float sum = 0.f;
  #pragma unroll
  for (int d = 0; d < 6; ++d) { lg[d] = expf(lg[d] - m); sum += lg[d]; }
  float inv = 1.f / sum;
  #pragma unroll
  for (int d = 0; d < 6; ++d) A[b * 288 + h * 36 + c * 6 + d] = lg[d] * inv;
}

// ---------------- fc mix over the raw-reshape scramble (bf16 LDS staging, padded) ----------------
__global__ __launch_bounds__(384) void k_fc(const bf16_t* __restrict__ qkvd,
                                            const float* __restrict__ fcw,
                                            const float* __restrict__ fcb,
                                            bf16_t* __restrict__ fconv) {
  __shared__ bf16_t sin16[64 * 152];  // 19456 B, row stride 152 (uint4-aligned)
  __shared__ float sout[54 * 66];     // 14256 B, row stride 66
  int blk = blockIdx.x;
  int b = blk >> 10, p0 = (blk & 1023) << 6;
  const bf16_t* src = qkvd + (size_t)b * 144 * NP + (size_t)p0 * 144;
  const uint4* src4 = (const uint4*)src;
  for (int i = threadIdx.x; i < 1152; i += 384) {
    uint4 u = src4[i];
    int pix = i / 18, sub = i % 18;   // 18 uint4 (=144 bf16) per pixel
    *(uint4*)&sin16[pix * 152 + sub * 8] = u;
  }
  __syncthreads();
  int pl = threadIdx.x / 6, c2 = threadIdx.x % 6;
  float xv[24];
  #pragma unroll
  for (int g = 0; g < 24; ++g) xv[g] = bf2f(sin16[pl * 152 + g * 6 + c2]);
  #pragma unroll
  for (int o = 0; o < 9; ++o) {
    float a = fcb[o];
    #pragma unroll
    for (int g = 0; g < 24; ++g) a += fcw[o * 24 + g] * xv[g];
    sout[(c2 * 9 + o) * 66 + pl] = a;
  }
  __syncthreads();
  for (int i = threadIdx.x; i < 1728; i += 384) {
    int ch = i >> 5, pr = (i & 31) * 2;
    *(ushort2*)(fconv + (size_t)(b * 54 + ch) * NP + p0 + pr) =
        make_ushort2(f2bf(sout[ch * 66 + pr]), f2bf(sout[ch * 66 + pr + 1]));
  }
}

// ---------------- grouped dep conv 54->48 (4-row stripe, bf16 LDS staging) ----------------
__global__ __launch_bounds__(256, 4) void k_depconv(const bf16_t* __restrict__ fconv,
                                                    const float* __restrict__ dw,
                                                    const float* __restrict__ db,
                                                    bf16_t* __restrict__ outconv) {
  __shared__ bf16_t lds16[9 * 6 * 272];  // 29376 B
  int blk = blockIdx.x;               // b*6*64 + g*64 + rq
  int rq = blk & 63;
  int g = (blk >> 6) % 6;
  int b = blk / (6 * 64);
  int yy0 = rq * 4;
  const bf16_t* fb = fconv + (size_t)(b * 54 + g * 9) * NP;
  for (int i = threadIdx.x; i < 9 * 6 * 68; i += 256) {
    int j = i / 408;
    int rem = i % 408;
    int sr = rem / 68, c4 = rem % 68;
    int iy = yy0 + sr - 1;
    ushort4 v = make_ushort4(0, 0, 0, 0);
    if ((unsigned)iy < (unsigned)NH && c4 >= 1 && c4 <= 64)
      v = *(const ushort4*)(fb + (size_t)j * NP + iy * NW + (c4 - 1) * 4);
    *(ushort4*)(&lds16[(j * 6 + sr) * 272 + c4 * 4]) = v;
  }
  __syncthreads();
  int q = threadIdx.x >> 6;
  int quad = threadIdx.x & 63;
  float acc[8][4];
  #pragma unroll
  for (int o = 0; o < 8; ++o) {
    float bv = db[g * 8 + o];
    #pragma unroll
    for (int jj = 0; jj < 4; ++jj) acc[o][jj] = bv;
  }
  const float* wg = dw + (size_t)(g * 8) * 81;
  #pragma unroll
  for (int j = 0; j < 9; ++j) {
    #pragma unroll
    for (int rr = 0; rr < 3; ++rr) {
      const bf16_t* lp = &lds16[((j * 6) + q + rr) * 272 + quad * 4];
      ushort4 ua = *(const ushort4*)lp;
      ushort4 ub = *(const ushort4*)(lp + 4);
      ushort4 uc = *(const ushort4*)(lp + 8);
      float v[12] = {bf2f(ua.x), bf2f(ua.y), bf2f(ua.z), bf2f(ua.w),
                     bf2f(ub.x), bf2f(ub.y), bf2f(ub.z), bf2f(ub.w),
                     bf2f(uc.x), bf2f(uc.y), bf2f(uc.z), bf2f(uc.w)};
      #pragma unroll
      for (int dxi = 0; dxi < 3; ++dxi) {
        int wi = j * 9 + rr * 3 + dxi;
        #pragma unroll
        for (int o = 0; o < 8; ++o) {
          float wv = wg[o * 81 + wi];
          #pragma unroll
          for (int jj = 0; jj < 4; ++jj)
            acc[o][jj] = fmaf(v[jj + dxi + 3], wv, acc[o][jj]);
        }
      }
    }
  }
  bf16_t* ob = outconv + ((size_t)(b * NC + g * 8) * NH + yy0 + q) * NW + quad * 4;
  #pragma unroll
  for (int o = 0; o < 8; ++o)
    *(ushort4*)(ob + (size_t)o * NP) =
        make_ushort4(f2bf(acc[o][0]), f2bf(acc[o][1]), f2bf(acc[o][2]), f2bf(acc[o][3]));
}

// ---------------- proj via MFMA: x1(bf16) = x + projw@(A@V) + outconv ----------------
__global__ __launch_bounds__(256) void k_proj_mfma(const bf16_t* __restrict__ qkvd,
                                                   const float* __restrict__ A,
                                                   const bf16_t* __restrict__ WJ,
                                                   const float* __restrict__ x,
                                                   const bf16_t* __restrict__ outconv,
                                                   bf16_t* __restrict__ x1) {
  __shared__ bf16_t vT[64 * 72];   // 9216 B
  __shared__ bf16_t avT[64 * 72];  // 9216 B
  __shared__ float sA[288];
  int blk = blockIdx.x;
  int pxt = blk & 1023;
  int b = blk >> 10;
  int pbase = pxt * 64;
  const bf16_t* vb = qkvd + (size_t)(b * 144 + 96) * NP + pbase;
  int p4 = threadIdx.x & 15, k0 = threadIdx.x >> 4;
  #pragma unroll
  for (int it = 0; it < 3; ++it) {
    int k = k0 + it * 16;
    ushort4 u = *(const ushort4*)(vb + (size_t)k * NP + p4 * 4);
    vT[(p4 * 4 + 0) * 72 + k] = u.x;
    vT[(p4 * 4 + 1) * 72 + k] = u.y;
    vT[(p4 * 4 + 2) * 72 + k] = u.z;
    vT[(p4 * 4 + 3) * 72 + k] = u.w;
  }
  {  // zero-pad avT k = 48..63 (done by the k0 sweep: 16 values per px)
    int k = 48 + k0;
    avT[(p4 * 4 + 0) * 72 + k] = 0;
    avT[(p4 * 4 + 1) * 72 + k] = 0;
    avT[(p4 * 4 + 2) * 72 + k] = 0;
    avT[(p4 * 4 + 3) * 72 + k] = 0;
  }
  for (int i = threadIdx.x; i < 288; i += 256) sA[i] = A[b * 288 + i];
  __syncthreads();
  {  // A@V: 4 threads per pixel, 2 heads each
    int px = threadIdx.x & 63, hh = threadIdx.x >> 6;
    #pragma unroll
    for (int hi = 0; hi < 2; ++hi) {
      int h = hh * 2 + hi;
      float v6[6];
      #pragma unroll
      for (int d = 0; d < 6; ++d) v6[d] = bf2f(vT[px * 72 + h * 6 + d]);
      #pragma unroll
      for (int c = 0; c < 6; ++c) {
        float av = 0.f;
        #pragma unroll
        for (int d = 0; d < 6; ++d) av = fmaf(sA[h * 36 + c * 6 + d], v6[d], av);
        avT[px * 72 + h * 6 + c] = f2bf(av);
      }
    }
  }
  __syncthreads();
  int w = threadIdx.x >> 6;
  int lane = threadIdx.x & 63;
  int prow = w * 16 + (lane & 15);
  bf16x8 f0 = *(const bf16x8*)&avT[prow * 72 + ((lane >> 4) << 3)];
  bf16x8 f1 = *(const bf16x8*)&avT[prow * 72 + 32 + ((lane >> 4) << 3)];
  int p = pbase + prow;
  const float* xb = x + (size_t)b * NC * NP + p;
  const bf16_t* ob = outconv + (size_t)b * NC * NP + p;
  bf16_t* x1b = x1 + (size_t)b * NC * NP + p;
  #pragma unroll
  for (int ot = 0; ot < 3; ++ot) {
    bf16x8 a0 = *(const bf16x8*)(WJ + (size_t)(ot * 2 + 0) * 512 + lane * 8);
    bf16x8 a1 = *(const bf16x8*)(WJ + (size_t)(ot * 2 + 1) * 512 + lane * 8);
    f32x4 acc = {0.f, 0.f, 0.f, 0.f};
    acc = __builtin_amdgcn_mfma_f32_16x16x32_bf16(a0, f0, acc, 0, 0, 0);
    acc = __builtin_amdgcn_mfma_f32_16x16x32_bf16(a1, f1, acc, 0, 0, 0);
    int orow = ot * 16 + ((lane >> 4) << 2);
    #pragma unroll
    for (int j = 0; j < 4; ++j) {
      int o = orow + j;
      x1b[(size_t)o * NP] = f2bf(xb[(size_t)o * NP] + acc[j] + bf2f(ob[(size_t)o * NP]));
    }
  }
}

// ---------------- FF: 3-dilation depthwise + gelu gate (div-free staging) ----------------
__global__ __launch_bounds__(256) void k_ffdw(const bf16_t* __restrict__ y,
                                              const float* __restrict__ w1,
                                              const float* __restrict__ w2,
                                              const float* __restrict__ w3,
                                              bf16_t* __restrict__ z) {
  __shared__ float lds[24 * 272];  // 26112 B
  int blk = blockIdx.x;
  int rq = blk & 63;
  int ch = (blk >> 6) % NHID;
  int b = blk / (NHID * 64);
  int yy0 = rq * 4;
  const bf16_t* yb = y + (size_t)(b * 288 + ch) * NP;
  // halo columns (x<0 and x>=256) are outside the image for every block -> zero
  if (threadIdx.x < 96) {
    int sr = threadIdx.x >> 2, part = threadIdx.x & 3;
    int slot = (part == 0) ? 0 : (256 + part * 4);  // 0 | 260 | 264 | 268
    *(float4*)(&lds[sr * 272 + slot]) = make_float4(0.f, 0.f, 0.f, 0.f);
  }
  // interior: 24 rows x 64 float4 groups; slot = x + 4
  #pragma unroll
  for (int it = 0; it < 6; ++it) {
    int sr = (threadIdx.x >> 6) + it * 4;
    int m = threadIdx.x & 63;
    int br, iy;
    if (sr < 6)       { br = 0; iy = yy0 + sr - 1; }
    else if (sr < 14) { br = 1; iy = yy0 + sr - 8; }
    else              { br = 2; iy = yy0 + sr - 17; }
    float4 v = make_float4(0.f, 0.f, 0.f, 0.f);
    if ((unsigned)iy < (unsigned)NH) {
      ushort4 u = *(const ushort4*)(yb + (size_t)(br * NHID) * NP + iy * NW + m * 4);
      v = make_float4(bf2f(u.x), bf2f(u.y), bf2f(u.z), bf2f(u.w));
    }
    *(float4*)(&lds[sr * 272 + 4 + m * 4]) = v;
  }
  __syncthreads();
  int q = threadIdx.x >> 6;
  int quad = threadIdx.x & 63;
  const float* wp1 = w1 + ch * 9;   // wave-uniform -> scalar loads
  const float* wp2 = w2 + ch * 9;
  const float* wp3 = w3 + ch * 9;
  float c1[4] = {0.f, 0.f, 0.f, 0.f};
  float c2[4] = {0.f, 0.f, 0.f, 0.f};
  float c3[4] = {0.f, 0.f, 0.f, 0.f};
  #pragma unroll
  for (int rr = 0; rr < 3; ++rr)
    STENCIL_ROW(0 + q + rr * 1, 1, wp1[rr * 3 + 0], wp1[rr * 3 + 1], wp1[rr * 3 + 2], c1);
  #pragma unroll
  for (int rr = 0; rr < 3; ++rr)
    STENCIL_ROW(6 + q + rr * 2, 2, wp2[rr * 3 + 0], wp2[rr * 3 + 1], wp2[rr * 3 + 2], c2);
  #pragma unroll
  for (int rr = 0; rr < 3; ++rr)
    STENCIL_ROW(14 + q + rr * 3, 3, wp3[rr * 3 + 0], wp3[rr * 3 + 1], wp3[rr * 3 + 2], c3);
  *(ushort4*)(z + (size_t)(b * NHID + ch) * NP + (yy0 + q) * NW + quad * 4) =
      make_ushort4(f2bf(gelu_f(c1[0]) * c2[0] * c3[0]),
                   f2bf(gelu_f(c1[1]) * c2[1] * c3[1]),
                   f2bf(gelu_f(c1[2]) * c2[2] * c3[2]),
                   f2bf(gelu_f(c1[3]) * c2[3] * c3[3]));
}

// ---------------- pout via MFMA: out[o][p] = x1[o][p] + (poutw @ z)[o][p] ----------------
__global__ __launch_bounds__(256) void k_pout_mfma(const bf16_t* __restrict__ z,
                                                   const bf16_t* __restrict__ WP,
                                                   const bf16_t* __restrict__ x1,
                                                   float* __restrict__ outp) {
  __shared__ bf16_t zT[64 * 104];  // 13312 B, row stride 104
  int blk = blockIdx.x;
  int pxt = blk & 1023;
  int b = blk >> 10;
  int pbase = pxt * 64;
  const bf16_t* zb = z + (size_t)b * NHID * NP + pbase;
  int p4 = threadIdx.x & 15, k0 = threadIdx.x >> 4;
  #pragma unroll
  for (int it = 0; it < 6; ++it) {
    int k = k0 + it * 16;
    ushort4 u = *(const ushort4*)(zb + (size_t)k * NP + p4 * 4);
    zT[(p4 * 4 + 0) * 104 + k] = u.x;
    zT[(p4 * 4 + 1) * 104 + k] = u.y;
    zT[(p4 * 4 + 2) * 104 + k] = u.z;
    zT[(p4 * 4 + 3) * 104 + k] = u.w;
  }
  __syncthreads();
  int w = threadIdx.x >> 6;
  int lane = threadIdx.x & 63;
  int prow = w * 16 + (lane & 15);
  bf16x8 bfr[3];
  #pragma unroll
  for (int s = 0; s < 3; ++s)
    bfr[s] = *(const bf16x8*)&zT[prow * 104 + s * 32 + ((lane >> 4) << 3)];
  int p = pbase + prow;
  const bf16_t* x1b = x1 + (size_t)b * NC * NP + p;
  float* ob = outp + (size_t)b * NC * NP + p;
  #pragma unroll
  for (int ot = 0; ot < 3; ++ot) {
    f32x4 acc = {0.f, 0.f, 0.f, 0.f};
    #pragma unroll
    for (int s = 0; s < 3; ++s) {
      bf16x8 a = *(const bf16x8*)(WP + (size_t)(ot * 3 + s) * 512 + lane * 8);
      acc = __builtin_amdgcn_mfma_f32_16x16x32_bf16(a, bfr[s], acc, 0, 0, 0);
    }
    int orow = ot * 16 + ((lane >> 4) << 2);
    #pragma unroll
    for (int j = 0; j < 4; ++j) {
      int o = orow + j;
      ob[(size_t)o * NP] = bf2f(x1b[(size_t)o * NP]) + acc[j];
    }
  }
}

// ---------------- workspace layout (float offsets; bf16 buffers use half) ----------------
constexpr size_t SZ_QKV = (size_t)NB * 144 * NP;
constexpr size_t SZ_CHW = (size_t)NB * NC * NP;
constexpr size_t OFF_QKV0 = 0;
constexpr size_t OFF_QKVD = OFF_QKV0 + SZ_QKV;         // bf16 buffers: region oversized, fine
constexpr size_t OFF_FCONV = OFF_QKVD + SZ_QKV;
constexpr size_t SZ_FCONV = (size_t)NB * 54 * NP;
constexpr size_t OFF_OUTCONV = OFF_FCONV + SZ_FCONV;
constexpr size_t OFF_X1 = OFF_OUTCONV + SZ_CHW;        // x1 bf16 (region oversized)
constexpr size_t OFF_STATS = OFF_X1 + SZ_CHW;          // repurposed: spart (512*48 <= NB*NP*2)
constexpr size_t OFF_T1 = OFF_STATS + (size_t)NB * NP * 2;  // t1 (conv, bf16) -> later SB/WA1/WA2/WP/WJ
constexpr size_t OFF_P1 = OFF_T1 + (size_t)NB * NC * 128 * 128;
constexpr size_t OFF_T2 = OFF_P1 + (size_t)NB * NC * 64 * 64;
constexpr size_t OFF_P2 = OFF_T2 + (size_t)NB * NC * 32 * 32;
constexpr size_t OFF_T3 = OFF_P2 + (size_t)NB * NC * 16 * 16;
constexpr size_t OFF_P3 = OFF_T3 + (size_t)NB * NC * 8 * 8;
constexpr size_t OFF_Q0M = OFF_P3 + (size_t)NB * NC * 4 * 4;
constexpr size_t OFF_NORMS = OFF_Q0M + 576;
constexpr size_t OFF_SPART = OFF_NORMS + 192;          // repurposed: A (576 floats)
constexpr size_t OFF_A = OFF_SPART + (size_t)NB * 64 * 48;

extern "C" void kernel_launch(void* const* d_in, const int* in_sizes, int n_in,
                              void* d_out, int out_size, void* d_ws, size_t ws_size,
                              hipStream_t stream) {
  const float* x     = (const float*)d_in[0];
  const float* ln1w  = (const float*)d_in[1];
  const float* ln1b  = (const float*)d_in[2];
  const float* qkvw  = (const float*)d_in[3];
  const float* qkvdw = (const float*)d_in[4];
  const float* projw = (const float*)d_in[5];
  const float* fcw   = (const float*)d_in[6];
  const float* fcb   = (const float*)d_in[7];
  const float* depw  = (const float*)d_in[8];
  const float* depb  = (const float*)d_in[9];
  const float* l2qw  = (const float*)d_in[10];
  const float* l2qb  = (const float*)d_in[11];
  const float* temp  = (const float*)d_in[12];
  const float* ln2w  = (const float*)d_in[13];
  const float* ln2b  = (const float*)d_in[14];
  const float* pinw  = (const float*)d_in[15];
  const float* dw1   = (const float*)d_in[16];
  const float* dw2   = (const float*)d_in[17];
  const float* dw3   = (const float*)d_in[18];
  const float* poutw = (const float*)d_in[19];
  const float* cvw0  = (const float*)d_in[20];
  const float* cvb0  = (const float*)d_in[21];
  const float* clw0  = (const float*)d_in[22];
  const float* clb0  = (const float*)d_in[23];
  const float* cvw1  = (const float*)d_in[24];
  const float* cvb1  = (const float*)d_in[25];
  const float* clw1  = (const float*)d_in[26];
  const float* clb1  = (const float*)d_in[27];
  const float* cvw2  = (const float*)d_in[28];
  const float* cvb2  = (const float*)d_in[29];
  const float* clw2  = (const float*)d_in[30];
  const float* clb2  = (const float*)d_in[31];

  float* ws = (float*)d_ws;
  bf16_t* qkv0 = (bf16_t*)(ws + OFF_QKV0);
  bf16_t* qkvd = (bf16_t*)(ws + OFF_QKVD);
  bf16_t* fconv = (bf16_t*)(ws + OFF_FCONV);
  bf16_t* outconv = (bf16_t*)(ws + OFF_OUTCONV);
  bf16_t* x1 = (bf16_t*)(ws + OFF_X1);
  bf16_t* t1b = (bf16_t*)(ws + OFF_T1);   // conv1 output, bf16
  float* p1 = ws + OFF_P1;
  float* t2 = ws + OFF_T2;
  float* p2 = ws + OFF_P2;
  float* t3 = ws + OFF_T3;
  float* p3 = ws + OFF_P3;
  float* q0m = ws + OFF_Q0M;
  float* spart = ws + OFF_STATS;      // 512*48 floats (fits 262144 region)
  float* A = ws + OFF_SPART;          // 576 floats
  // SB/WA1/WA2/WP/WJ live in the t1 region: t1 is dead after the first lnpool
  // and never touched again; k_prep runs after the conv branch (in-stream).
  float* SB = ws + OFF_T1;                                           // 864 floats
  bf16_t* WA1 = (bf16_t*)(ws + OFF_T1 + 1024);                       // 9216 bf16
  bf16_t* WA2 = (bf16_t*)(ws + OFF_T1 + 1024 + 4608);                // 18432 bf16
  bf16_t* WP  = (bf16_t*)(ws + OFF_T1 + 1024 + 4608 + 9216);         // 4608 bf16
  bf16_t* WJ  = (bf16_t*)(ws + OFF_T1 + 1024 + 4608 + 9216 + 2304);  // 3072 bf16
  // WC (conv1 fragments) lives in the qkv0 region: needed only during conv1,
  // which runs before anything writes qkv0 (k_chmix is after k_prep).
  bf16_t* WC = (bf16_t*)(ws + OFF_QKV0);                             // 27648 bf16
  bf16_t* ybuf = (bf16_t*)(ws + OFF_QKV0);   // reuse qkv0 region (bf16, fits)
  bf16_t* zbuf = (bf16_t*)(ws + OFF_FCONV);  // reuse fconv region (bf16, fits)

  // conv-descriptor branch: conv1 via MFMA (weights prepacked into dead region)
  k_prepw<<<108, 256, 0, stream>>>(cvw0, WC);
  k_conv1_mfma<<<512, 512, 0, stream>>>(x, WC, cvb0, t1b);
  k_lnpool_b<<<128, 256, 0, stream>>>(t1b, clw0, clb0, p1, 128, 128);
  k_conv_s2_tile<<<32, 512, 0, stream>>>(p1, cvw1, cvb1, t2, 64, 64, 32, 32);
  k_lnpool<<<8, 256, 0, stream>>>(t2, clw1, clb1, p2, 32, 32);
  k_conv_s2_tile<<<2, 512, 0, stream>>>(p2, cvw2, cvb2, t3, 16, 16, 8, 8);
  k_lnpool<<<1, 256, 0, stream>>>(t3, clw2, clb2, p3, 8, 8);
  k_head<<<2, 320, 0, stream>>>(p3, l2qw, l2qb, q0m);

  // LN folding + MFMA fragment packing (t1 region is dead by now)
  k_prep<<<8, 256, 0, stream>>>(qkvw, ln1w, ln1b, pinw, ln2w, ln2b, poutw, projw,
                                SB, WA1, WA2, WP, WJ);

  // attention
  k_chmix_mfma<<<NB * 1024, 256, 0, stream>>>(x, WA1, SB, SB + 144, qkv0, 144);
  k_dw144<<<NB * 144 * 32, 256, 0, stream>>>(qkv0, qkvdw, qkvd);
  k_gram<<<NB * NHEADS * GSEG, 256, 0, stream>>>(qkvd, spart);
  k_attn<<<2, 256, 0, stream>>>(spart, temp, q0m, A);
  k_fc<<<2048, 384, 0, stream>>>(qkvd, fcw, fcb, fconv);
  k_depconv<<<768, 256, 0, stream>>>(fconv, depw, depb, outconv);
  k_proj_mfma<<<NB * 1024, 256, 0, stream>>>(qkvd, A, WJ, x, outconv, x1);

  // feedforward
  k_chmix_mfma_b<<<NB * 1024, 256, 0, stream>>>(x1, WA2, SB + 288, SB + 576, ybuf, 288);
  k_ffdw<<<NB * NHID * 64, 256, 0, stream>>>(ybuf, dw1, dw2, dw3, zbuf);
  k_pout_mfma<<<NB * 1024, 256, 0, stream>>>(zbuf, WP, x1, (float*)d_out);
}

// Round 32
// 310.401 us; speedup vs baseline: 1.0390x; 1.0065x over previous
//
#include <hip/hip_runtime.h>

constexpr int NB = 2;
constexpr int NC = 48;
constexpr int NH = 256;
constexpr int NW = 256;
constexpr int NP = NH * NW;           // 65536
constexpr int NHEADS = 8;
constexpr int NCHD = 6;
constexpr int NHID = 96;
constexpr int GSEG = 32;              // gram segments per (b,h)

typedef unsigned short bf16_t;
typedef __attribute__((ext_vector_type(8))) short bf16x8;
typedef __attribute__((ext_vector_type(4))) float f32x4;

__device__ __forceinline__ float bf2f(bf16_t u) {
  union { unsigned int i; float f; } c; c.i = ((unsigned int)u) << 16; return c.f;
}
__device__ __forceinline__ bf16_t f2bf(float f) {
  union { float f; unsigned int i; } c; c.f = f;
  unsigned int r = (c.i + 0x7FFFu + ((c.i >> 16) & 1u)) >> 16;
  return (bf16_t)r;
}
__device__ __forceinline__ void unpack2(unsigned int u, float& a, float& b) {
  union { unsigned int i; float f; } c0, c1;
  c0.i = u << 16; c1.i = u & 0xffff0000u;
  a = c0.f; b = c1.f;
}

// tanh-form GELU via fast exp (max dev vs erf-form ~3e-4)
__device__ __forceinline__ float gelu_f(float v) {
  float u = v * (0.79788456f + 0.0356774081f * v * v);
  u = fminf(fmaxf(u, -9.f), 9.f);
  float e = __expf(-2.f * u);
  float th = (1.f - e) / (1.f + e);
  return 0.5f * v * (1.f + th);
}

// tap loop over a 12-float window (3x ds_read_b128), compile-time indices.
#define STENCIL_ROW(LROW, D, WVAL0, WVAL1, WVAL2, ACC)                        \
  {                                                                            \
    const float* lp = &lds[(LROW) * 272 + quad * 4];                           \
    float4 va = *(const float4*)lp;                                            \
    float4 vb = *(const float4*)(lp + 4);                                      \
    float4 vc = *(const float4*)(lp + 8);                                      \
    float v[12] = {va.x, va.y, va.z, va.w, vb.x, vb.y, vb.z, vb.w,             \
                   vc.x, vc.y, vc.z, vc.w};                                    \
    _Pragma("unroll") for (int jj = 0; jj < 4; ++jj) {                         \
      ACC[jj] = fmaf(v[jj - (D) + 4], WVAL0, ACC[jj]);                         \
      ACC[jj] = fmaf(v[jj + 4], WVAL1, ACC[jj]);                               \
      ACC[jj] = fmaf(v[jj + (D) + 4], WVAL2, ACC[jj]);                         \
    }                                                                          \
  }

// ---------------- conv1 weight prepack: per-tap MFMA A-fragments ----------------
__global__ void k_prepw(const float* __restrict__ cvw0, bf16_t* __restrict__ WC) {
  int i = blockIdx.x * blockDim.x + threadIdx.x;
  if (i >= 9 * 3 * 2 * 512) return;
  int j = i & 7, lane = (i >> 3) & 63;
  int fi = i >> 9;
  int s = fi & 1;
  int tot = fi >> 1;
  int ot = tot % 3, t = tot / 3;
  int o = ot * 16 + (lane & 15);
  int k = s * 32 + ((lane >> 4) << 3) + j;
  float v = (k < 48) ? cvw0[(size_t)(o * 48 + k) * 9 + t] : 0.f;
  WC[i] = f2bf(v);
}

// ---------------- conv1 via MFMA: 8x8 out tile, split-K, vectorized interior staging ----------------
__global__ __launch_bounds__(512) void k_conv1_mfma(const float* __restrict__ in,
                                                    const bf16_t* __restrict__ WC,
                                                    const float* __restrict__ bias,
                                                    bf16_t* __restrict__ out) {
  __shared__ bf16_t xs[17 * 17 * 72];   // 41616 B, [iy][ix][ic] ic-stride 72
  __shared__ float red[4 * 3 * 64 * 4]; // 12288 B split-K partials
  int blk = blockIdx.x;
  int tx = blk & 15;
  int t0 = blk >> 4;
  int ty = t0 & 15, b = t0 >> 4;
  int oy0 = ty * 8, ox0 = tx * 8;
  int iy0 = oy0 * 2 - 1, ix0 = ox0 * 2 - 1;
  const float* inb = in + (size_t)b * NC * NP;
  if (tx > 0 && ty > 0) {
    // interior: rows fully in-bounds; 5 aligned float4 per 17-wide row
    int bx = ix0 - 3;  // byte offset 16*(4*tx-1) -> 16B aligned
    for (int v = threadIdx.x; v < 48 * 17 * 5; v += 512) {
      int part = v % 5;
      int row = v / 5;
      int rr = row % 17;
      int ic = row / 17;
      const float* src = inb + ((size_t)ic << 16) + ((size_t)(iy0 + rr) << 8) + bx + part * 4;
      float4 f = *(const float4*)src;
      float fv[4] = {f.x, f.y, f.z, f.w};
      int cc0 = part * 4 - 3;
      #pragma unroll
      for (int e = 0; e < 4; ++e) {
        int cc = cc0 + e;
        if ((unsigned)cc < 17u) xs[(rr * 17 + cc) * 72 + ic] = f2bf(fv[e]);
      }
    }
  } else {
    for (int i = threadIdx.x; i < 17 * 17 * 48; i += 512) {
      int cc = i % 17;
      int t2 = i / 17;
      int rr = t2 % 17;
      int ic = t2 / 17;
      float v = 0.f;
      int iy = iy0 + rr, ix = ix0 + cc;
      if ((unsigned)iy < 256u && (unsigned)ix < 256u)
        v = inb[((size_t)ic << 16) + (iy << 8) + ix];
      xs[(rr * 17 + cc) * 72 + ic] = f2bf(v);
    }
  }
  for (int i = threadIdx.x; i < 289 * 16; i += 512) {  // zero-pad k 48..63
    int rcc = i >> 4, icz = i & 15;
    xs[rcc * 72 + 48 + icz] = 0;
  }
  __syncthreads();
  int wid = threadIdx.x >> 6, lane = threadIdx.x & 63;
  int pt = wid & 3, s = wid >> 2;
  int l15 = lane & 15, kl = lane >> 4;
  int px = pt * 16 + l15;
  int oy = px >> 3, ox = px & 7;
  int base = ((oy * 2) * 17 + ox * 2) * 72 + s * 32 + kl * 8;
  f32x4 acc[3] = {{0.f, 0.f, 0.f, 0.f}, {0.f, 0.f, 0.f, 0.f}, {0.f, 0.f, 0.f, 0.f}};
  #pragma unroll
  for (int t = 0; t < 9; ++t) {
    int dy = t / 3, dx = t % 3;  // compile-time
    bf16x8 bf = *(const bf16x8*)&xs[base + dy * (17 * 72) + dx * 72];
    #pragma unroll
    for (int ot = 0; ot < 3; ++ot) {
      bf16x8 af = *(const bf16x8*)(WC + (size_t)((t * 3 + ot) * 2 + s) * 512 + lane * 8);
      acc[ot] = __builtin_amdgcn_mfma_f32_16x16x32_bf16(af, bf, acc[ot], 0, 0, 0);
    }
  }
  if (s == 1) {
    #pragma unroll
    for (int ot = 0; ot < 3; ++ot)
      #pragma unroll
      for (int j = 0; j < 4; ++j)
        red[((pt * 3 + ot) * 64 + lane) * 4 + j] = acc[ot][j];
  }
  __syncthreads();
  if (s == 0) {
    bf16_t* ob = out + (size_t)b * NC * 16384;
    #pragma unroll
    for (int ot = 0; ot < 3; ++ot) {
      #pragma unroll
      for (int j = 0; j < 4; ++j) {
        int o = ot * 16 + kl * 4 + j;
        float r = acc[ot][j] + red[((pt * 3 + ot) * 64 + lane) * 4 + j] + bias[o];
        ob[((size_t)o * 128 + oy0 + oy) * 128 + ox0 + ox] = f2bf(r);
      }
    }
  }
}

// ---------------- conv-descriptor branch (conv2/conv3): ic-chunked, 8-wave blocks ----------------
__global__ __launch_bounds__(512) void k_conv_s2_tile(const float* __restrict__ in,
                                                      const float* __restrict__ w,
                                                      const float* __restrict__ bias,
                                                      float* __restrict__ out,
                                                      int IH, int IW, int OH, int OW) {
  __shared__ float lds[16 * 442];  // 16 ic * 17 rows * 26 = 28288 B
  int tilesX = OW >> 3;
  int tilesY = OH >> 3;
  int blk = blockIdx.x;
  int tx = blk % tilesX;
  int t = blk / tilesX;
  int ty = t % tilesY;
  int b = t / tilesY;
  int oy0 = ty * 8, ox0 = tx * 8;
  int iy0 = oy0 * 2 - 1, ix0 = ox0 * 2 - 1;
  const float* inb = in + (size_t)b * NC * IH * IW;

  int lane = threadIdx.x & 63;
  int oy = lane >> 3, ox = lane & 7;
  int ocb = __builtin_amdgcn_readfirstlane((threadIdx.x >> 6) * 6);
  float acc[6];
  #pragma unroll
  for (int j = 0; j < 6; ++j) acc[j] = bias[ocb + j];
  int rbase = oy * 52;  // row 2*oy, stride 26

  for (int chunk = 0; chunk < 3; ++chunk) {
    int icb = chunk * 16;
    for (int i = threadIdx.x; i < 16 * 17 * 17; i += 512) {
      int cc = i % 17;
      int t2 = i / 17;
      int rr = t2 % 17;
      int ic = t2 / 17;
      float v = 0.f;
      int iy = iy0 + rr, ix = ix0 + cc;
      if ((unsigned)iy < (unsigned)IH && (unsigned)ix < (unsigned)IW)
        v = inb[((size_t)(icb + ic) * IH + iy) * IW + ix];
      lds[ic * 442 + rr * 26 + ((cc & 1) ? 13 + (cc >> 1) : (cc >> 1))] = v;
    }
    __syncthreads();

    for (int ic16 = 0; ic16 < 16; ++ic16) {
      const float* base = lds + ic16 * 442 + rbase;
      float e0[3], e1[3], ov[3];
      #pragma unroll
      for (int ky = 0; ky < 3; ++ky) {
        const float* rowp = base + ky * 26;
        e0[ky] = rowp[ox];
        e1[ky] = rowp[ox + 1];
        ov[ky] = rowp[13 + ox];
      }
      const float* wpc = w + (size_t)(ocb * 48 + icb + ic16) * 9;
      #pragma unroll
      for (int j = 0; j < 6; ++j) {
        const float* wp = wpc + (size_t)j * 48 * 9;
        float a = acc[j];
        #pragma unroll
        for (int ky = 0; ky < 3; ++ky) {
          a = fmaf(wp[ky * 3 + 0], e0[ky], a);
          a = fmaf(wp[ky * 3 + 1], ov[ky], a);
          a = fmaf(wp[ky * 3 + 2], e1[ky], a);
        }
        acc[j] = a;
      }
    }
    __syncthreads();
  }

  float* ob = out + (size_t)b * NC * OH * OW;
  #pragma unroll
  for (int j = 0; j < 6; ++j)
    ob[((size_t)(ocb + j) * OH + oy0 + oy) * OW + ox0 + ox] = acc[j];
}

// ---------------- lnpool (f32 input): 4 sublanes share the channel loop ----------------
__global__ void k_lnpool(const float* __restrict__ in, const float* __restrict__ lw,
                         const float* __restrict__ lb, float* __restrict__ out,
                         int IH, int IW) {
  int OH = IH >> 1, OW = IW >> 1;
  int tid = blockIdx.x * blockDim.x + threadIdx.x;
  int idx = tid >> 2;
  int sl = tid & 3;        // channels sl*12 .. sl*12+11
  int total = NB * OH * OW;
  if (idx >= total) return;
  int ox = idx % OW;
  int t = idx / OW;
  int oy = t % OH;
  int b = t / OH;
  const float* inb = in + (size_t)b * NC * IH * IW;
  float vq[12][4];
  float s[4] = {0.f, 0.f, 0.f, 0.f}, ss[4] = {0.f, 0.f, 0.f, 0.f};
  #pragma unroll
  for (int cl = 0; cl < 12; ++cl) {
    int c = sl * 12 + cl;
    #pragma unroll
    for (int q = 0; q < 4; ++q) {
      int iy = oy * 2 + (q >> 1), ix = ox * 2 + (q & 1);
      float v = inb[((size_t)c * IH + iy) * IW + ix];
      vq[cl][q] = v;
      s[q] += v;
      ss[q] = fmaf(v, v, ss[q]);
    }
  }
  #pragma unroll
  for (int q = 0; q < 4; ++q) {
    s[q] += __shfl_xor(s[q], 1, 64);
    s[q] += __shfl_xor(s[q], 2, 64);
    ss[q] += __shfl_xor(ss[q], 1, 64);
    ss[q] += __shfl_xor(ss[q], 2, 64);
  }
  float mu[4], rs[4];
  #pragma unroll
  for (int q = 0; q < 4; ++q) {
    float m = s[q] * (1.f / NC);
    mu[q] = m;
    rs[q] = rsqrtf(fmaxf(ss[q] * (1.f / NC) - m * m, 0.f) + 1e-5f);
  }
  #pragma unroll
  for (int cl = 0; cl < 12; ++cl) {
    int c = sl * 12 + cl;
    float wv = lw[c], bv = lb[c];
    float best = 0.f;  // relu >= 0 so 0 == max of relu'd window
    #pragma unroll
    for (int q = 0; q < 4; ++q) {
      float v = (vq[cl][q] - mu[q]) * rs[q] * wv + bv;
      best = fmaxf(best, fmaxf(v, 0.f));
    }
    out[((size_t)(b * NC + c) * OH + oy) * OW + ox] = best;
  }
}

// ---------------- lnpool (bf16 input, stage 1) ----------------
__global__ void k_lnpool_b(const bf16_t* __restrict__ in, const float* __restrict__ lw,
                           const float* __restrict__ lb, float* __restrict__ out,
                           int IH, int IW) {
  int OH = IH >> 1, OW = IW >> 1;
  int tid = blockIdx.x * blockDim.x + threadIdx.x;
  int idx = tid >> 2;
  int sl = tid & 3;        // channels sl*12 .. sl*12+11
  int total = NB * OH * OW;
  if (idx >= total) return;
  int ox = idx % OW;
  int t = idx / OW;
  int oy = t % OH;
  int b = t / OH;
  const bf16_t* inb = in + (size_t)b * NC * IH * IW;
  float vq[12][4];
  float s[4] = {0.f, 0.f, 0.f, 0.f}, ss[4] = {0.f, 0.f, 0.f, 0.f};
  #pragma unroll
  for (int cl = 0; cl < 12; ++cl) {
    int c = sl * 12 + cl;
    #pragma unroll
    for (int q = 0; q < 4; ++q) {
      int iy = oy * 2 + (q >> 1), ix = ox * 2 + (q & 1);
      float v = bf2f(inb[((size_t)c * IH + iy) * IW + ix]);
      vq[cl][q] = v;
      s[q] += v;
      ss[q] = fmaf(v, v, ss[q]);
    }
  }
  #pragma unroll
  for (int q = 0; q < 4; ++q) {
    s[q] += __shfl_xor(s[q], 1, 64);
    s[q] += __shfl_xor(s[q], 2, 64);
    ss[q] += __shfl_xor(ss[q], 1, 64);
    ss[q] += __shfl_xor(ss[q], 2, 64);
  }
  float mu[4], rs[4];
  #pragma unroll
  for (int q = 0; q < 4; ++q) {
    float m = s[q] * (1.f / NC);
    mu[q] = m;
    rs[q] = rsqrtf(fmaxf(ss[q] * (1.f / NC) - m * m, 0.f) + 1e-5f);
  }
  #pragma unroll
  for (int cl = 0; cl < 12; ++cl) {
    int c = sl * 12 + cl;
    float wv = lw[c], bv = lb[c];
    float best = 0.f;
    #pragma unroll
    for (int q = 0; q < 4; ++q) {
      float v = (vq[cl][q] - mu[q]) * rs[q] * wv + bv;
      best = fmaxf(best, fmaxf(v, 0.f));
    }
    out[((size_t)(b * NC + c) * OH + oy) * OW + ox] = best;
  }
}

__global__ void k_head(const float* __restrict__ p3, const float* __restrict__ l2qw,
                       const float* __restrict__ l2qb, float* __restrict__ q0m) {
  __shared__ float xd[NC], q0[NC];
  int b = blockIdx.x, t = threadIdx.x;
  if (t < NC) {
    float s = 0.f;
    for (int i = 0; i < 16; ++i) s += p3[(b * NC + t) * 16 + i];
    xd[t] = gelu_f(s * (1.f / 16.f));
  }
  __syncthreads();
  if (t < NC) {
    float a = l2qb[t];
    for (int c = 0; c < NC; ++c) a += xd[c] * l2qw[t * NC + c];
    q0[t] = a;
  }
  __syncthreads();
  if (t < NHEADS * NCHD * NCHD) {
    int h = t / 36, r = t % 36, c = r / 6, d = r % 6;
    q0m[b * 288 + t] = q0[h * 6 + c] * q0[h * 6 + d];
  }
}

// ---------------- prep: S/B vectors + bf16 A-fragment-packed weights (qkv, pin, pout, proj) ----------------
__global__ void k_prep(const float* __restrict__ qkvw, const float* __restrict__ ln1w,
                       const float* __restrict__ ln1b, const float* __restrict__ pinw,
                       const float* __restrict__ ln2w, const float* __restrict__ ln2b,
                       const float* __restrict__ poutw, const float* __restrict__ projw,
                       float* __restrict__ SB, bf16_t* __restrict__ WA1,
                       bf16_t* __restrict__ WA2, bf16_t* __restrict__ WP,
                       bf16_t* __restrict__ WJ) {
  int t = blockIdx.x * blockDim.x + threadIdx.x;
  int stride = gridDim.x * blockDim.x;
  if (t < 144) {
    float s = 0.f, bb = 0.f;
    for (int c = 0; c < 48; ++c) {
      float w = qkvw[t * 48 + c];
      s = fmaf(w, ln1w[c], s); bb = fmaf(w, ln1b[c], bb);
    }
    SB[t] = s; SB[144 + t] = bb;
  } else if (t < 144 + 288) {
    int o = t - 144;
    float s = 0.f, bb = 0.f;
    for (int c = 0; c < 48; ++c) {
      float w = pinw[o * 48 + c];
      s = fmaf(w, ln2w[c], s); bb = fmaf(w, ln2b[c], bb);
    }
    SB[288 + o] = s; SB[576 + o] = bb;
  }
  for (int i = t; i < 9 * 1024; i += stride) {   // 144 oc: 9 ot * 2 s * 64 lane * 8 j
    int j = i & 7, lane = (i >> 3) & 63, s = (i >> 9) & 1, ot = i >> 10;
    int o = ot * 16 + (lane & 15);
    int k = s * 32 + ((lane >> 4) << 3) + j;
    float v = (k < 48) ? qkvw[o * 48 + k] * ln1w[k] : 0.f;
    WA1[i] = f2bf(v);
  }
  for (int i = t; i < 18 * 1024; i += stride) {  // 288 oc: 18 ot
    int j = i & 7, lane = (i >> 3) & 63, s = (i >> 9) & 1, ot = i >> 10;
    int o = ot * 16 + (lane & 15);
    int k = s * 32 + ((lane >> 4) << 3) + j;
    float v = (k < 48) ? pinw[o * 48 + k] * ln2w[k] : 0.f;
    WA2[i] = f2bf(v);
  }
  for (int i = t; i < 9 * 512; i += stride) {    // pout: 3 ot * 3 s * 512
    int j = i & 7, lane = (i >> 3) & 63;
    int fi = i >> 9;
    int s = fi % 3, ot = fi / 3;
    int o = ot * 16 + (lane & 15);
    int k = s * 32 + ((lane >> 4) << 3) + j;
    WP[i] = f2bf(poutw[o * 96 + k]);
  }
  for (int i = t; i < 6 * 512; i += stride) {    // proj: 3 ot * 2 s * 512
    int j = i & 7, lane = (i >> 3) & 63;
    int fi = i >> 9;
    int s = fi & 1, ot = fi >> 1;
    int o = ot * 16 + (lane & 15);
    int k = s * 32 + ((lane >> 4) << 3) + j;
    float v = (k < 48) ? projw[o * 48 + k] : 0.f;
    WJ[i] = f2bf(v);
  }
}

// ---------------- channel-mix via MFMA: 64-px tile, bf16 fragments (f32 input) ----------------
// out[o][p] = rstd[p]*(mfma(W',xT)[o][p] - mu[p]*S[o]) + B[o]
__global__ __launch_bounds__(256) void k_chmix_mfma(const float* __restrict__ x,
                                                    const bf16_t* __restrict__ WA,
                                                    const float* __restrict__ S,
                                                    const float* __restrict__ Bc,
                                                    bf16_t* __restrict__ out,
                                                    int nout) {
  __shared__ bf16_t xT[64 * 72];       // 9216 B, row stride 72 (2-way bank alias)
  __shared__ float smu[64], srstd[64];
  int blk = blockIdx.x;
  int pxt = blk & 1023;
  int b = blk >> 10;
  int pbase = pxt * 64;
  const float* xb = x + (size_t)b * NC * NP + pbase;
  int p4 = threadIdx.x & 15, k0 = threadIdx.x >> 4;
  #pragma unroll
  for (int it = 0; it < 3; ++it) {
    int k = k0 + it * 16;
    float4 v = *(const float4*)(xb + (size_t)k * NP + p4 * 4);
    xT[(p4 * 4 + 0) * 72 + k] = f2bf(v.x);
    xT[(p4 * 4 + 1) * 72 + k] = f2bf(v.y);
    xT[(p4 * 4 + 2) * 72 + k] = f2bf(v.z);
    xT[(p4 * 4 + 3) * 72 + k] = f2bf(v.w);
  }
  {  // zero-pad k = 48..63
    int k = 48 + k0;
    xT[(p4 * 4 + 0) * 72 + k] = 0;
    xT[(p4 * 4 + 1) * 72 + k] = 0;
    xT[(p4 * 4 + 2) * 72 + k] = 0;
    xT[(p4 * 4 + 3) * 72 + k] = 0;
  }
  __syncthreads();
  if (threadIdx.x < 64) {
    int t = threadIdx.x;
    float s = 0.f, ss = 0.f;
    #pragma unroll
    for (int k4 = 0; k4 < 12; ++k4) {
      ushort4 u = *(const ushort4*)&xT[t * 72 + k4 * 4];
      float a0 = bf2f(u.x), a1 = bf2f(u.y), a2 = bf2f(u.z), a3 = bf2f(u.w);
      s += a0 + a1 + a2 + a3;
      ss = fmaf(a0, a0, ss); ss = fmaf(a1, a1, ss);
      ss = fmaf(a2, a2, ss); ss = fmaf(a3, a3, ss);
    }
    float mu = s * (1.f / NC);
    smu[t] = mu;
    srstd[t] = rsqrtf(fmaxf(ss * (1.f / NC) - mu * mu, 0.f) + 1e-5f);
  }
  int w = threadIdx.x >> 6;
  int lane = threadIdx.x & 63;
  bf16x8 bfr0 = *(const bf16x8*)&xT[(w * 16 + (lane & 15)) * 72 + ((lane >> 4) << 3)];
  bf16x8 bfr1 = *(const bf16x8*)&xT[(w * 16 + (lane & 15)) * 72 + 32 + ((lane >> 4) << 3)];
  __syncthreads();
  float mu = smu[w * 16 + (lane & 15)];
  float rs = srstd[w * 16 + (lane & 15)];
  int p = pbase + w * 16 + (lane & 15);
  int nt = nout >> 4;
  bf16_t* ob = out + (size_t)b * nout * NP + p;
  for (int ot = 0; ot < nt; ++ot) {
    bf16x8 a0 = *(const bf16x8*)(WA + (size_t)(ot * 2 + 0) * 512 + lane * 8);
    bf16x8 a1 = *(const bf16x8*)(WA + (size_t)(ot * 2 + 1) * 512 + lane * 8);
    f32x4 acc = {0.f, 0.f, 0.f, 0.f};
    acc = __builtin_amdgcn_mfma_f32_16x16x32_bf16(a0, bfr0, acc, 0, 0, 0);
    acc = __builtin_amdgcn_mfma_f32_16x16x32_bf16(a1, bfr1, acc, 0, 0, 0);
    int orow = ot * 16 + ((lane >> 4) << 2);
    #pragma unroll
    for (int j = 0; j < 4; ++j) {
      int o = orow + j;
      float r = fmaf(rs, acc[j] - mu * S[o], Bc[o]);
      ob[(size_t)o * NP] = f2bf(r);
    }
  }
}

// ---------------- channel-mix via MFMA, bf16 input (for x1) ----------------
__global__ __launch_bounds__(256) void k_chmix_mfma_b(const bf16_t* __restrict__ x,
                                                      const bf16_t* __restrict__ WA,
                                                      const float* __restrict__ S,
                                                      const float* __restrict__ Bc,
                                                      bf16_t* __restrict__ out,
                                                      int nout) {
  __shared__ bf16_t xT[64 * 72];
  __shared__ float smu[64], srstd[64];
  int blk = blockIdx.x;
  int pxt = blk & 1023;
  int b = blk >> 10;
  int pbase = pxt * 64;
  const bf16_t* xb = x + (size_t)b * NC * NP + pbase;
  int p4 = threadIdx.x & 15, k0 = threadIdx.x >> 4;
  #pragma unroll
  for (int it = 0; it < 3; ++it) {
    int k = k0 + it * 16;
    ushort4 u = *(const ushort4*)(xb + (size_t)k * NP + p4 * 4);
    xT[(p4 * 4 + 0) * 72 + k] = u.x;
    xT[(p4 * 4 + 1) * 72 + k] = u.y;
    xT[(p4 * 4 + 2) * 72 + k] = u.z;
    xT[(p4 * 4 + 3) * 72 + k] = u.w;
  }
  {  // zero-pad k = 48..63
    int k = 48 + k0;
    xT[(p4 * 4 + 0) * 72 + k] = 0;
    xT[(p4 * 4 + 1) * 72 + k] = 0;
    xT[(p4 * 4 + 2) * 72 + k] = 0;
    xT[(p4 * 4 + 3) * 72 + k] = 0;
  }
  __syncthreads();
  if (threadIdx.x < 64) {
    int t = threadIdx.x;
    float s = 0.f, ss = 0.f;
    #pragma unroll
    for (int k4 = 0; k4 < 12; ++k4) {
      ushort4 u = *(const ushort4*)&xT[t * 72 + k4 * 4];
      float a0 = bf2f(u.x), a1 = bf2f(u.y), a2 = bf2f(u.z), a3 = bf2f(u.w);
      s += a0 + a1 + a2 + a3;
      ss = fmaf(a0, a0, ss); ss = fmaf(a1, a1, ss);
      ss = fmaf(a2, a2, ss); ss = fmaf(a3, a3, ss);
    }
    float mu = s * (1.f / NC);
    smu[t] = mu;
    srstd[t] = rsqrtf(fmaxf(ss * (1.f / NC) - mu * mu, 0.f) + 1e-5f);
  }
  int w = threadIdx.x >> 6;
  int lane = threadIdx.x & 63;
  bf16x8 bfr0 = *(const bf16x8*)&xT[(w * 16 + (lane & 15)) * 72 + ((lane >> 4) << 3)];
  bf16x8 bfr1 = *(const bf16x8*)&xT[(w * 16 + (lane & 15)) * 72 + 32 + ((lane >> 4) << 3)];
  __syncthreads();
  float mu = smu[w * 16 + (lane & 15)];
  float rs = srstd[w * 16 + (lane & 15)];
  int p = pbase + w * 16 + (lane & 15);
  int nt = nout >> 4;
  bf16_t* ob = out + (size_t)b * nout * NP + p;
  for (int ot = 0; ot < nt; ++ot) {
    bf16x8 a0 = *(const bf16x8*)(WA + (size_t)(ot * 2 + 0) * 512 + lane * 8);
    bf16x8 a1 = *(const bf16x8*)(WA + (size_t)(ot * 2 + 1) * 512 + lane * 8);
    f32x4 acc = {0.f, 0.f, 0.f, 0.f};
    acc = __builtin_amdgcn_mfma_f32_16x16x32_bf16(a0, bfr0, acc, 0, 0, 0);
    acc = __builtin_amdgcn_mfma_f32_16x16x32_bf16(a1, bfr1, acc, 0, 0, 0);
    int orow = ot * 16 + ((lane >> 4) << 2);
    #pragma unroll
    for (int j = 0; j < 4; ++j) {
      int o = orow + j;
      float r = fmaf(rs, acc[j] - mu * S[o], Bc[o]);
      ob[(size_t)o * NP] = f2bf(r);
    }
  }
}

// ---------------- depthwise 3x3 on 144 channels (8-row stripe, XCD-swizzled) ----------------
__global__ __launch_bounds__(256) void k_dw144(const bf16_t* __restrict__ in,
                                               const float* __restrict__ w9,
                                               bf16_t* __restrict__ out) {
  __shared__ float lds[10 * 272];  // 10880 B
  // XCD-aware bijective swizzle: grid = NB*144*32 = 9216, 9216/8 = 1152
  int bid = blockIdx.x;
  int blk = (bid & 7) * 1152 + (bid >> 3);
  int rq = blk & 31;
  int ch = (blk >> 5) % 144;
  int b = blk / (144 * 32);
  int yy0 = rq * 8;
  const bf16_t* ib = in + (size_t)(b * 144 + ch) * NP;
  if (threadIdx.x < 40) {  // x-halo zeros: 10 rows x {slot0, 260,264,268}
    int sr = threadIdx.x >> 2, part = threadIdx.x & 3;
    int slot = (part == 0) ? 0 : (256 + part * 4);
    *(float4*)(&lds[sr * 272 + slot]) = make_float4(0.f, 0.f, 0.f, 0.f);
  }
  for (int i = threadIdx.x; i < 640; i += 256) {  // 10 rows x 64 float4 groups
    int sr = i >> 6, m = i & 63;
    int iy = yy0 + sr - 1;
    float4 v = make_float4(0.f, 0.f, 0.f, 0.f);
    if ((unsigned)iy < (unsigned)NH) {
      ushort4 u = *(const ushort4*)(ib + iy * NW + m * 4);
      v = make_float4(bf2f(u.x), bf2f(u.y), bf2f(u.z), bf2f(u.w));
    }
    *(float4*)(&lds[sr * 272 + 4 + m * 4]) = v;
  }
  __syncthreads();
  int q = threadIdx.x >> 6;
  int quad = threadIdx.x & 63;
  const float* wp = w9 + ch * 9;   // wave-uniform -> scalar loads
  bf16_t* ob = out + (size_t)(b * 144 + ch) * NP;
  #pragma unroll
  for (int half = 0; half < 2; ++half) {
    int orow = q + half * 4;
    float acc[4] = {0.f, 0.f, 0.f, 0.f};
    #pragma unroll
    for (int rr = 0; rr < 3; ++rr)
      STENCIL_ROW(orow + rr, 1, wp[rr * 3 + 0], wp[rr * 3 + 1], wp[rr * 3 + 2], acc);
    *(ushort4*)(ob + (yy0 + orow) * NW + quad * 4) =
        make_ushort4(f2bf(acc[0]), f2bf(acc[1]), f2bf(acc[2]), f2bf(acc[3]));
  }
}

// ---------------- per-head Gram (36) + channel ssq (12), GSEG=32, split-butterfly reduce ----------------
__global__ __launch_bounds__(256) void k_gram(const bf16_t* __restrict__ qkvd,
                                              float* __restrict__ spart) {
  int gid = blockIdx.x;  // b*256 + h*32 + seg
  int seg = gid & (GSEG - 1), h = (gid >> 5) & 7, b = gid >> 8;
  const bf16_t* qb = qkvd + (size_t)(b * 144 + h * 6) * NP;
  const bf16_t* kb = qkvd + (size_t)(b * 144 + 48 + h * 6) * NP;
  float acc[48];
  #pragma unroll
  for (int j = 0; j < 48; ++j) acc[j] = 0.f;
  #pragma unroll
  for (int it = 0; it < 2; ++it) {
    int p0 = seg * (NP / GSEG) + it * 1024 + threadIdx.x * 4;
    float qv[6][4], kv[6][4];
    #pragma unroll
    for (int c = 0; c < 6; ++c) {
      ushort4 uq = *(const ushort4*)(qb + (size_t)c * NP + p0);
      qv[c][0] = bf2f(uq.x); qv[c][1] = bf2f(uq.y); qv[c][2] = bf2f(uq.z); qv[c][3] = bf2f(uq.w);
      ushort4 uk = *(const ushort4*)(kb + (size_t)c * NP + p0);
      kv[c][0] = bf2f(uk.x); kv[c][1] = bf2f(uk.y); kv[c][2] = bf2f(uk.z); kv[c][3] = bf2f(uk.w);
    }
    #pragma unroll
    for (int px = 0; px < 4; ++px) {
      #pragma unroll
      for (int c = 0; c < 6; ++c)
        #pragma unroll
        for (int d = 0; d < 6; ++d)
          acc[c * 6 + d] = fmaf(qv[c][px], kv[d][px], acc[c * 6 + d]);
      #pragma unroll
      for (int c = 0; c < 6; ++c) acc[36 + c] = fmaf(qv[c][px], qv[c][px], acc[36 + c]);
      #pragma unroll
      for (int d = 0; d < 6; ++d) acc[42 + d] = fmaf(kv[d][px], kv[d][px], acc[42 + d]);
    }
  }
  int lane = threadIdx.x & 63, wid = threadIdx.x >> 6;
  // split-butterfly: halve the j-set at each xor step (compile-time indices)
  bool h1 = (lane & 32) != 0;
  float r1[24];
  #pragma unroll
  for (int m = 0; m < 24; ++m) {
    float keep = h1 ? acc[m + 24] : acc[m];
    float send = h1 ? acc[m] : acc[m + 24];
    r1[m] = keep + __shfl_xor(send, 32, 64);
  }
  bool h2 = (lane & 16) != 0;
  float r2[12];
  #pragma unroll
  for (int m = 0; m < 12; ++m) {
    float keep = h2 ? r1[m + 12] : r1[m];
    float send = h2 ? r1[m] : r1[m + 12];
    r2[m] = keep + __shfl_xor(send, 16, 64);
  }
  bool h3 = (lane & 8) != 0;
  float r3[6];
  #pragma unroll
  for (int m = 0; m < 6; ++m) {
    float keep = h3 ? r2[m + 6] : r2[m];
    float send = h3 ? r2[m] : r2[m + 6];
    r3[m] = keep + __shfl_xor(send, 8, 64);
  }
  bool h4 = (lane & 4) != 0;
  float r4[3];
  #pragma unroll
  for (int m = 0; m < 3; ++m) {
    float keep = h4 ? r3[m + 3] : r3[m];
    float send = h4 ? r3[m] : r3[m + 3];
    r4[m] = keep + __shfl_xor(send, 4, 64);
    r4[m] += __shfl_xor(r4[m], 2, 64);
    r4[m] += __shfl_xor(r4[m], 1, 64);
  }
  int jb = (h1 ? 24 : 0) + (h2 ? 12 : 0) + (h3 ? 6 : 0) + (h4 ? 3 : 0);
  __shared__ float sr[4 * 48];
  if ((lane & 3) == 0) {
    #pragma unroll
    for (int m = 0; m < 3; ++m) sr[wid * 48 + jb + m] = r4[m];
  }
  __syncthreads();
  if (threadIdx.x < 48)
    spart[(size_t)gid * 48 + threadIdx.x] =
        sr[threadIdx.x] + sr[48 + threadIdx.x] + sr[96 + threadIdx.x] + sr[144 + threadIdx.x];
}

// ---------------- attention softmax (cooperative seg reduce + softmax) ----------------
__global__ __launch_bounds__(256) void k_attn(const float* __restrict__ spart,
                                              const float* __restrict__ temp,
                                              const float* __restrict__ q0m,
                                              float* __restrict__ A) {
  int b = blockIdx.x;
  __shared__ float tot[8 * 48];
  for (int j = threadIdx.x; j < 384; j += 256) {
    int h = j / 48, v = j % 48;
    const float* base = spart + ((size_t)(b * 8 + h) * GSEG) * 48 + v;
    float s = 0.f;
    for (int seg = 0; seg < GSEG; ++seg) s += base[(size_t)seg * 48];
    tot[j] = s;
  }
  __syncthreads();
  int t = threadIdx.x;
  if (t >= 48) return;
  int h = t / 6, c = t % 6;
  const float* T = &tot[h * 48];
  float nq = fmaxf(sqrtf(T[36 + c]), 1e-12f);
  float tm = temp[h];
  float lg[6];
  #pragma unroll
  for (int d = 0; d < 6; ++d) {
    float nk = fmaxf(sqrtf(T[42 + d]), 1e-12f);
    lg[d] = (T[c * 6 + d] / (nq * nk)) * tm * q0m[b * 288 + h * 36 + c * 6 + d];
  }
  float m = lg[0];
  #pragma unroll
  for (int d = 1; d < 6; ++d) m = fmaxf(m, lg[d]);
  float sum = 0.f;
  #pragma unroll
  for (int d = 0; d < 6; ++d) { lg[d] = expf(lg[d] - m); sum += lg[d]; }
  float inv = 1.f / sum;
  #pragma unroll
  for (int d = 0; d < 6; ++d) A[b * 288 + h * 36 + c * 6 + d] = lg[d] * inv;
}

// ---------------- fc mix over the raw-reshape scramble (bf16 LDS staging, padded) ----------------
__global__ __launch_bounds__(384) void k_fc(const bf16_t* __restrict__ qkvd,
                                            const float* __restrict__ fcw,
                                            const float* __restrict__ fcb,
                                            bf16_t* __restrict__ fconv) {
  __shared__ bf16_t sin16[64 * 152];  // 19456 B, row stride 152 (uint4-aligned)
  __shared__ float sout[54 * 66];     // 14256 B, row stride 66
  int blk = blockIdx.x;
  int b = blk >> 10, p0 = (blk & 1023) << 6;
  const bf16_t* src = qkvd + (size_t)b * 144 * NP + (size_t)p0 * 144;
  const uint4* src4 = (const uint4*)src;
  for (int i = threadIdx.x; i < 1152; i += 384) {
    uint4 u = src4[i];
    int pix = i / 18, sub = i % 18;   // 18 uint4 (=144 bf16) per pixel
    *(uint4*)&sin16[pix * 152 + sub * 8] = u;
  }
  __syncthreads();
  int pl = threadIdx.x / 6, c2 = threadIdx.x % 6;
  float xv[24];
  #pragma unroll
  for (int g = 0; g < 24; ++g) xv[g] = bf2f(sin16[pl * 152 + g * 6 + c2]);
  #pragma unroll
  for (int o = 0; o < 9; ++o) {
    float a = fcb[o];
    #pragma unroll
    for (int g = 0; g < 24; ++g) a += fcw[o * 24 + g] * xv[g];
    sout[(c2 * 9 + o) * 66 + pl] = a;
  }
  __syncthreads();
  for (int i = threadIdx.x; i < 1728; i += 384) {
    int ch = i >> 5, pr = (i & 31) * 2;
    *(ushort2*)(fconv + (size_t)(b * 54 + ch) * NP + p0 + pr) =
        make_ushort2(f2bf(sout[ch * 66 + pr]), f2bf(sout[ch * 66 + pr + 1]));
  }
}

// ---------------- grouped dep conv 54->48 (4-row stripe, XCD-swizzled) ----------------
__global__ __launch_bounds__(256, 4) void k_depconv(const bf16_t* __restrict__ fconv,
                                                    const float* __restrict__ dw,
                                                    const float* __restrict__ db,
                                                    bf16_t* __restrict__ outconv) {
  __shared__ bf16_t lds16[9 * 6 * 272];  // 29376 B
  // XCD-aware bijective swizzle: grid = 768, 768/8 = 96
  int bid = blockIdx.x;
  int blk = (bid & 7) * 96 + (bid >> 3);   // b*6*64 + g*64 + rq
  int rq = blk & 63;
  int g = (blk >> 6) % 6;
  int b = blk / (6 * 64);
  int yy0 = rq * 4;
  const bf16_t* fb = fconv + (size_t)(b * 54 + g * 9) * NP;
  for (int i = threadIdx.x; i < 9 * 6 * 68; i += 256) {
    int j = i / 408;
    int rem = i % 408;
    int sr = rem / 68, c4 = rem % 68;
    int iy = yy0 + sr - 1;
    ushort4 v = make_ushort4(0, 0, 0, 0);
    if ((unsigned)iy < (unsigned)NH && c4 >= 1 && c4 <= 64)
      v = *(const ushort4*)(fb + (size_t)j * NP + iy * NW + (c4 - 1) * 4);
    *(ushort4*)(&lds16[(j * 6 + sr) * 272 + c4 * 4]) = v;
  }
  __syncthreads();
  int q = threadIdx.x >> 6;
  int quad = threadIdx.x & 63;
  float acc[8][4];
  #pragma unroll
  for (int o = 0; o < 8; ++o) {
    float bv = db[g * 8 + o];
    #pragma unroll
    for (int jj = 0; jj < 4; ++jj) acc[o][jj] = bv;
  }
  const float* wg = dw + (size_t)(g * 8) * 81;
  #pragma unroll
  for (int j = 0; j < 9; ++j) {
    #pragma unroll
    for (int rr = 0; rr < 3; ++rr) {
      const bf16_t* lp = &lds16[((j * 6) + q + rr) * 272 + quad * 4];
      ushort4 ua = *(const ushort4*)lp;
      ushort4 ub = *(const ushort4*)(lp + 4);
      ushort4 uc = *(const ushort4*)(lp + 8);
      float v[12] = {bf2f(ua.x), bf2f(ua.y), bf2f(ua.z), bf2f(ua.w),
                     bf2f(ub.x), bf2f(ub.y), bf2f(ub.z), bf2f(ub.w),
                     bf2f(uc.x), bf2f(uc.y), bf2f(uc.z), bf2f(uc.w)};
      #pragma unroll
      for (int dxi = 0; dxi < 3; ++dxi) {
        int wi = j * 9 + rr * 3 + dxi;
        #pragma unroll
        for (int o = 0; o < 8; ++o) {
          float wv = wg[o * 81 + wi];
          #pragma unroll
          for (int jj = 0; jj < 4; ++jj)
            acc[o][jj] = fmaf(v[jj + dxi + 3], wv, acc[o][jj]);
        }
      }
    }
  }
  bf16_t* ob = outconv + ((size_t)(b * NC + g * 8) * NH + yy0 + q) * NW + quad * 4;
  #pragma unroll
  for (int o = 0; o < 8; ++o)
    *(ushort4*)(ob + (size_t)o * NP) =
        make_ushort4(f2bf(acc[o][0]), f2bf(acc[o][1]), f2bf(acc[o][2]), f2bf(acc[o][3]));
}

// ---------------- proj via MFMA: x1(bf16) = x + projw@(A@V) + outconv ----------------
__global__ __launch_bounds__(256) void k_proj_mfma(const bf16_t* __restrict__ qkvd,
                                                   const float* __restrict__ A,
                                                   const bf16_t* __restrict__ WJ,
                                                   const float* __restrict__ x,
                                                   const bf16_t* __restrict__ outconv,
                                                   bf16_t* __restrict__ x1) {
  __shared__ bf16_t vT[64 * 72];   // 9216 B
  __shared__ bf16_t avT[64 * 72];  // 9216 B
  __shared__ float sA[288];
  int blk = blockIdx.x;
  int pxt = blk & 1023;
  int b = blk >> 10;
  int pbase = pxt * 64;
  const bf16_t* vb = qkvd + (size_t)(b * 144 + 96) * NP + pbase;
  int p4 = threadIdx.x & 15, k0 = threadIdx.x >> 4;
  #pragma unroll
  for (int it = 0; it < 3; ++it) {
    int k = k0 + it * 16;
    ushort4 u = *(const ushort4*)(vb + (size_t)k * NP + p4 * 4);
    vT[(p4 * 4 + 0) * 72 + k] = u.x;
    vT[(p4 * 4 + 1) * 72 + k] = u.y;
    vT[(p4 * 4 + 2) * 72 + k] = u.z;
    vT[(p4 * 4 + 3) * 72 + k] = u.w;
  }
  {  // zero-pad avT k = 48..63 (done by the k0 sweep: 16 values per px)
    int k = 48 + k0;
    avT[(p4 * 4 + 0) * 72 + k] = 0;
    avT[(p4 * 4 + 1) * 72 + k] = 0;
    avT[(p4 * 4 + 2) * 72 + k] = 0;
    avT[(p4 * 4 + 3) * 72 + k] = 0;
  }
  for (int i = threadIdx.x; i < 288; i += 256) sA[i] = A[b * 288 + i];
  __syncthreads();
  {  // A@V: 4 threads per pixel, 2 heads each
    int px = threadIdx.x & 63, hh = threadIdx.x >> 6;
    #pragma unroll
    for (int hi = 0; hi < 2; ++hi) {
      int h = hh * 2 + hi;
      float v6[6];
      #pragma unroll
      for (int d = 0; d < 6; ++d) v6[d] = bf2f(vT[px * 72 + h * 6 + d]);
      #pragma unroll
      for (int c = 0; c < 6; ++c) {
        float av = 0.f;
        #pragma unroll
        for (int d = 0; d < 6; ++d) av = fmaf(sA[h * 36 + c * 6 + d], v6[d], av);
        avT[px * 72 + h * 6 + c] = f2bf(av);
      }
    }
  }
  __syncthreads();
  int w = threadIdx.x >> 6;
  int lane = threadIdx.x & 63;
  int prow = w * 16 + (lane & 15);
  bf16x8 f0 = *(const bf16x8*)&avT[prow * 72 + ((lane >> 4) << 3)];
  bf16x8 f1 = *(const bf16x8*)&avT[prow * 72 + 32 + ((lane >> 4) << 3)];
  int p = pbase + prow;
  const float* xb = x + (size_t)b * NC * NP + p;
  const bf16_t* ob = outconv + (size_t)b * NC * NP + p;
  bf16_t* x1b = x1 + (size_t)b * NC * NP + p;
  #pragma unroll
  for (int ot = 0; ot < 3; ++ot) {
    bf16x8 a0 = *(const bf16x8*)(WJ + (size_t)(ot * 2 + 0) * 512 + lane * 8);
    bf16x8 a1 = *(const bf16x8*)(WJ + (size_t)(ot * 2 + 1) * 512 + lane * 8);
    f32x4 acc = {0.f, 0.f, 0.f, 0.f};
    acc = __builtin_amdgcn_mfma_f32_16x16x32_bf16(a0, f0, acc, 0, 0, 0);
    acc = __builtin_amdgcn_mfma_f32_16x16x32_bf16(a1, f1, acc, 0, 0, 0);
    int orow = ot * 16 + ((lane >> 4) << 2);
    #pragma unroll
    for (int j = 0; j < 4; ++j) {
      int o = orow + j;
      x1b[(size_t)o * NP] = f2bf(xb[(size_t)o * NP] + acc[j] + bf2f(ob[(size_t)o * NP]));
    }
  }
}

// ---------------- FF: 3-dilation depthwise + gelu gate (XCD-swizzled) ----------------
__global__ __launch_bounds__(256) void k_ffdw(const bf16_t* __restrict__ y,
                                              const float* __restrict__ w1,
                                              const float* __restrict__ w2,
                                              const float* __restrict__ w3,
                                              bf16_t* __restrict__ z) {
  __shared__ float lds[24 * 272];  // 26112 B
  // XCD-aware bijective swizzle: grid = NB*NHID*64 = 12288, 12288/8 = 1536
  int bid = blockIdx.x;
  int blk = (bid & 7) * 1536 + (bid >> 3);
  int rq = blk & 63;
  int ch = (blk >> 6) % NHID;
  int b = blk / (NHID * 64);
  int yy0 = rq * 4;
  const bf16_t* yb = y + (size_t)(b * 288 + ch) * NP;
  // halo columns (x<0 and x>=256) are outside the image for every block -> zero
  if (threadIdx.x < 96) {
    int sr = threadIdx.x >> 2, part = threadIdx.x & 3;
    int slot = (part == 0) ? 0 : (256 + part * 4);  // 0 | 260 | 264 | 268
    *(float4*)(&lds[sr * 272 + slot]) = make_float4(0.f, 0.f, 0.f, 0.f);
  }
  // interior: 24 rows x 64 float4 groups; slot = x + 4
  #pragma unroll
  for (int it = 0; it < 6; ++it) {
    int sr = (threadIdx.x >> 6) + it * 4;
    int m = threadIdx.x & 63;
    int br, iy;
    if (sr < 6)       { br = 0; iy = yy0 + sr - 1; }
    else if (sr < 14) { br = 1; iy = yy0 + sr - 8; }
    else              { br = 2; iy = yy0 + sr - 17; }
    float4 v = make_float4(0.f, 0.f, 0.f, 0.f);
    if ((unsigned)iy < (unsigned)NH) {
      ushort4 u = *(const ushort4*)(yb + (size_t)(br * NHID) * NP + iy * NW + m * 4);
      v = make_float4(bf2f(u.x), bf2f(u.y), bf2f(u.z), bf2f(u.w));
    }
    *(float4*)(&lds[sr * 272 + 4 + m * 4]) = v;
  }
  __syncthreads();
  int q = threadIdx.x >> 6;
  int quad = threadIdx.x & 63;
  const float* wp1 = w1 + ch * 9;   // wave-uniform -> scalar loads
  const float* wp2 = w2 + ch * 9;
  const float* wp3 = w3 + ch * 9;
  float c1[4] = {0.f, 0.f, 0.f, 0.f};
  float c2[4] = {0.f, 0.f, 0.f, 0.f};
  float c3[4] = {0.f, 0.f, 0.f, 0.f};
  #pragma unroll
  for (int rr = 0; rr < 3; ++rr)
    STENCIL_ROW(0 + q + rr * 1, 1, wp1[rr * 3 + 0], wp1[rr * 3 + 1], wp1[rr * 3 + 2], c1);
  #pragma unroll
  for (int rr = 0; rr < 3; ++rr)
    STENCIL_ROW(6 + q + rr * 2, 2, wp2[rr * 3 + 0], wp2[rr * 3 + 1], wp2[rr * 3 + 2], c2);
  #pragma unroll
  for (int rr = 0; rr < 3; ++rr)
    STENCIL_ROW(14 + q + rr * 3, 3, wp3[rr * 3 + 0], wp3[rr * 3 + 1], wp3[rr * 3 + 2], c3);
  *(ushort4*)(z + (size_t)(b * NHID + ch) * NP + (yy0 + q) * NW + quad * 4) =
      make_ushort4(f2bf(gelu_f(c1[0]) * c2[0] * c3[0]),
                   f2bf(gelu_f(c1[1]) * c2[1] * c3[1]),
                   f2bf(gelu_f(c1[2]) * c2[2] * c3[2]),
                   f2bf(gelu_f(c1[3]) * c2[3] * c3[3]));
}

// ---------------- pout via MFMA: out[o][p] = x1[o][p] + (poutw @ z)[o][p] ----------------
__global__ __launch_bounds__(256) void k_pout_mfma(const bf16_t* __restrict__ z,
                                                   const bf16_t* __restrict__ WP,
                                                   const bf16_t* __restrict__ x1,
                                                   float* __restrict__ outp) {
  __shared__ bf16_t zT[64 * 104];  // 13312 B, row stride 104
  int blk = blockIdx.x;
  int pxt = blk & 1023;
  int b = blk >> 10;
  int pbase = pxt * 64;
  const bf16_t* zb = z + (size_t)b * NHID * NP + pbase;
  int p4 = threadIdx.x & 15, k0 = threadIdx.x >> 4;
  #pragma unroll
  for (int it = 0; it < 6; ++it) {
    int k = k0 + it * 16;
    ushort4 u = *(const ushort4*)(zb + (size_t)k * NP + p4 * 4);
    zT[(p4 * 4 + 0) * 104 + k] = u.x;
    zT[(p4 * 4 + 1) * 104 + k] = u.y;
    zT[(p4 * 4 + 2) * 104 + k] = u.z;
    zT[(p4 * 4 + 3) * 104 + k] = u.w;
  }
  __syncthreads();
  int w = threadIdx.x >> 6;
  int lane = threadIdx.x & 63;
  int prow = w * 16 + (lane & 15);
  bf16x8 bfr[3];
  #pragma unroll
  for (int s = 0; s < 3; ++s)
    bfr[s] = *(const bf16x8*)&zT[prow * 104 + s * 32 + ((lane >> 4) << 3)];
  int p = pbase + prow;
  const bf16_t* x1b = x1 + (size_t)b * NC * NP + p;
  float* ob = outp + (size_t)b * NC * NP + p;
  #pragma unroll
  for (int ot = 0; ot < 3; ++ot) {
    f32x4 acc = {0.f, 0.f, 0.f, 0.f};
    #pragma unroll
    for (int s = 0; s < 3; ++s) {
      bf16x8 a = *(const bf16x8*)(WP + (size_t)(ot * 3 + s) * 512 + lane * 8);
      acc = __builtin_amdgcn_mfma_f32_16x16x32_bf16(a, bfr[s], acc, 0, 0, 0);
    }
    int orow = ot * 16 + ((lane >> 4) << 2);
    #pragma unroll
    for (int j = 0; j < 4; ++j) {
      int o = orow + j;
      ob[(size_t)o * NP] = bf2f(x1b[(size_t)o * NP]) + acc[j];
    }
  }
}

// ---------------- workspace layout (float offsets; bf16 buffers use half) ----------------
constexpr size_t SZ_QKV = (size_t)NB * 144 * NP;
constexpr size_t SZ_CHW = (size_t)NB * NC * NP;
constexpr size_t OFF_QKV0 = 0;
constexpr size_t OFF_QKVD = OFF_QKV0 + SZ_QKV;         // bf16 buffers: region oversized, fine
constexpr size_t OFF_FCONV = OFF_QKVD + SZ_QKV;
constexpr size_t SZ_FCONV = (size_t)NB * 54 * NP;
constexpr size_t OFF_OUTCONV = OFF_FCONV + SZ_FCONV;
constexpr size_t OFF_X1 = OFF_OUTCONV + SZ_CHW;        // x1 bf16 (region oversized)
constexpr size_t OFF_STATS = OFF_X1 + SZ_CHW;          // repurposed: spart (512*48 <= NB*NP*2)
constexpr size_t OFF_T1 = OFF_STATS + (size_t)NB * NP * 2;  // t1 (conv, bf16) -> later SB/WA1/WA2/WP/WJ
constexpr size_t OFF_P1 = OFF_T1 + (size_t)NB * NC * 128 * 128;
constexpr size_t OFF_T2 = OFF_P1 + (size_t)NB * NC * 64 * 64;
constexpr size_t OFF_P2 = OFF_T2 + (size_t)NB * NC * 32 * 32;
constexpr size_t OFF_T3 = OFF_P2 + (size_t)NB * NC * 16 * 16;
constexpr size_t OFF_P3 = OFF_T3 + (size_t)NB * NC * 8 * 8;
constexpr size_t OFF_Q0M = OFF_P3 + (size_t)NB * NC * 4 * 4;
constexpr size_t OFF_NORMS = OFF_Q0M + 576;
constexpr size_t OFF_SPART = OFF_NORMS + 192;          // repurposed: A (576 floats)
constexpr size_t OFF_A = OFF_SPART + (size_t)NB * 64 * 48;

extern "C" void kernel_launch(void* const* d_in, const int* in_sizes, int n_in,
                              void* d_out, int out_size, void* d_ws, size_t ws_size,
                              hipStream_t stream) {
  const float* x     = (const float*)d_in[0];
  const float* ln1w  = (const float*)d_in[1];
  const float* ln1b  = (const float*)d_in[2];
  const float* qkvw  = (const float*)d_in[3];
  const float* qkvdw = (const float*)d_in[4];
  const float* projw = (const float*)d_in[5];
  const float* fcw   = (const float*)d_in[6];
  const float* fcb   = (const float*)d_in[7];
  const float* depw  = (const float*)d_in[8];
  const float* depb  = (const float*)d_in[9];
  const float* l2qw  = (const float*)d_in[10];
  const float* l2qb  = (const float*)d_in[11];
  const float* temp  = (const float*)d_in[12];
  const float* ln2w  = (const float*)d_in[13];
  const float* ln2b  = (const float*)d_in[14];
  const float* pinw  = (const float*)d_in[15];
  const float* dw1   = (const float*)d_in[16];
  const float* dw2   = (const float*)d_in[17];
  const float* dw3   = (const float*)d_in[18];
  const float* poutw = (const float*)d_in[19];
  const float* cvw0  = (const float*)d_in[20];
  const float* cvb0  = (const float*)d_in[21];
  const float* clw0  = (const float*)d_in[22];
  const float* clb0  = (const float*)d_in[23];
  const float* cvw1  = (const float*)d_in[24];
  const float* cvb1  = (const float*)d_in[25];
  const float* clw1  = (const float*)d_in[26];
  const float* clb1  = (const float*)d_in[27];
  const float* cvw2  = (const float*)d_in[28];
  const float* cvb2  = (const float*)d_in[29];
  const float* clw2  = (const float*)d_in[30];
  const float* clb2  = (const float*)d_in[31];

  float* ws = (float*)d_ws;
  bf16_t* qkv0 = (bf16_t*)(ws + OFF_QKV0);
  bf16_t* qkvd = (bf16_t*)(ws + OFF_QKVD);
  bf16_t* fconv = (bf16_t*)(ws + OFF_FCONV);
  bf16_t* outconv = (bf16_t*)(ws + OFF_OUTCONV);
  bf16_t* x1 = (bf16_t*)(ws + OFF_X1);
  bf16_t* t1b = (bf16_t*)(ws + OFF_T1);   // conv1 output, bf16
  float* p1 = ws + OFF_P1;
  float* t2 = ws + OFF_T2;
  float* p2 = ws + OFF_P2;
  float* t3 = ws + OFF_T3;
  float* p3 = ws + OFF_P3;
  float* q0m = ws + OFF_Q0M;
  float* spart = ws + OFF_STATS;      // 512*48 floats (fits 262144 region)
  float* A = ws + OFF_SPART;          // 576 floats
  // SB/WA1/WA2/WP/WJ live in the t1 region: t1 is dead after the first lnpool
  // and never touched again; k_prep runs after the conv branch (in-stream).
  float* SB = ws + OFF_T1;                                           // 864 floats
  bf16_t* WA1 = (bf16_t*)(ws + OFF_T1 + 1024);                       // 9216 bf16
  bf16_t* WA2 = (bf16_t*)(ws + OFF_T1 + 1024 + 4608);                // 18432 bf16
  bf16_t* WP  = (bf16_t*)(ws + OFF_T1 + 1024 + 4608 + 9216);         // 4608 bf16
  bf16_t* WJ  = (bf16_t*)(ws + OFF_T1 + 1024 + 4608 + 9216 + 2304);  // 3072 bf16
  // WC (conv1 fragments) lives in the qkv0 region: needed only during conv1,
  // which runs before anything writes qkv0 (k_chmix is after k_prep).
  bf16_t* WC = (bf16_t*)(ws + OFF_QKV0);                             // 27648 bf16
  bf16_t* ybuf = (bf16_t*)(ws + OFF_QKV0);   // reuse qkv0 region (bf16, fits)
  bf16_t* zbuf = (bf16_t*)(ws + OFF_FCONV);  // reuse fconv region (bf16, fits)

  // conv-descriptor branch: conv1 via MFMA (weights prepacked into dead region)
  k_prepw<<<108, 256, 0, stream>>>(cvw0, WC);
  k_conv1_mfma<<<512, 512, 0, stream>>>(x, WC, cvb0, t1b);
  k_lnpool_b<<<128, 256, 0, stream>>>(t1b, clw0, clb0, p1, 128, 128);
  k_conv_s2_tile<<<32, 512, 0, stream>>>(p1, cvw1, cvb1, t2, 64, 64, 32, 32);
  k_lnpool<<<8, 256, 0, stream>>>(t2, clw1, clb1, p2, 32, 32);
  k_conv_s2_tile<<<2, 512, 0, stream>>>(p2, cvw2, cvb2, t3, 16, 16, 8, 8);
  k_lnpool<<<1, 256, 0, stream>>>(t3, clw2, clb2, p3, 8, 8);
  k_head<<<2, 320, 0, stream>>>(p3, l2qw, l2qb, q0m);

  // LN folding + MFMA fragment packing (t1 region is dead by now)
  k_prep<<<8, 256, 0, stream>>>(qkvw, ln1w, ln1b, pinw, ln2w, ln2b, poutw, projw,
                                SB, WA1, WA2, WP, WJ);

  // attention
  k_chmix_mfma<<<NB * 1024, 256, 0, stream>>>(x, WA1, SB, SB + 144, qkv0, 144);
  k_dw144<<<NB * 144 * 32, 256, 0, stream>>>(qkv0, qkvdw, qkvd);
  k_gram<<<NB * NHEADS * GSEG, 256, 0, stream>>>(qkvd, spart);
  k_attn<<<2, 256, 0, stream>>>(spart, temp, q0m, A);
  k_fc<<<2048, 384, 0, stream>>>(qkvd, fcw, fcb, fconv);
  k_depconv<<<768, 256, 0, stream>>>(fconv, depw, depb, outconv);
  k_proj_mfma<<<NB * 1024, 256, 0, stream>>>(qkvd, A, WJ, x, outconv, x1);

  // feedforward
  k_chmix_mfma_b<<<NB * 1024, 256, 0, stream>>>(x1, WA2, SB + 288, SB + 576, ybuf, 288);
  k_ffdw<<<NB * NHID * 64, 256, 0, stream>>>(ybuf, dw1, dw2, dw3, zbuf);
  k_pout_mfma<<<NB * 1024, 256, 0, stream>>>(zbuf, WP, x1, (float*)d_out);
}